// Round 1
// baseline (451.050 us; speedup 1.0000x reference)
//
#include <hip/hip_runtime.h>

#define DIM 768
#define NEXP 4
#define DFF_ 1024
#define CAP 16384  // per-expert slot capacity (max possible = T)

typedef __attribute__((ext_vector_type(4))) float f32x4;
typedef __attribute__((ext_vector_type(8))) short s16x8;

__device__ __forceinline__ unsigned short f32_to_bf16(float f) {
  unsigned int u = __float_as_uint(f);
  unsigned int r = (u + 0x7FFFu + ((u >> 16) & 1u)) >> 16;  // RNE
  return (unsigned short)r;
}
__device__ __forceinline__ float bf16_to_f32(unsigned short u) {
  return __uint_as_float(((unsigned int)u) << 16);
}

// ---------- transpose fp32 [R,C] -> bf16, generalized output addressing ----------
__global__ void transpose_bf16_kernel(const float* __restrict__ in,
                                      unsigned short* __restrict__ out,
                                      int R, int C, int ldo, int zOut) {
  __shared__ float tile[32][33];
  const int bx = blockIdx.x, by = blockIdx.y, bz = blockIdx.z;
  in  += (size_t)bz * R * C;
  out += (size_t)bz * zOut;
  const int tx = threadIdx.x, ty = threadIdx.y;
#pragma unroll
  for (int i = 0; i < 4; i++) {
    int r = by * 32 + ty + i * 8;
    int c = bx * 32 + tx;
    tile[ty + i * 8][tx] = in[(size_t)r * C + c];
  }
  __syncthreads();
#pragma unroll
  for (int i = 0; i < 4; i++) {
    int oc = bx * 32 + ty + i * 8;
    int orow = by * 32 + tx;
    out[(size_t)oc * ldo + orow] = f32_to_bf16(tile[tx][ty + i * 8]);
  }
}

// ---------- Wfg = W @ Wg, bgp = b @ Wg + bg (fp32 router weights) ----------
__global__ void wfg_kernel(const float* __restrict__ W, const float* __restrict__ Wg,
                           const float* __restrict__ b, const float* __restrict__ bg,
                           float* __restrict__ wfg, float* __restrict__ bgp) {
  int gid = blockIdx.x * 256 + threadIdx.x;
  if (gid < DIM * NEXP) {
    int k = gid >> 2, e = gid & 3;
    const float* wr = W + (size_t)k * DIM;
    float acc = 0.f;
    for (int d = 0; d < DIM; d++) acc += wr[d] * Wg[d * NEXP + e];
    wfg[gid] = acc;
  } else if (gid < DIM * NEXP + NEXP) {
    int e = gid - DIM * NEXP;
    float acc = bg[e];
    for (int d = 0; d < DIM; d++) acc += b[d] * Wg[d * NEXP + e];
    bgp[e] = acc;
  }
}

// ---------- router (+ fused x->bf16 convert): fp32 logits, softmax, top2 ----------
__global__ void router_kernel(const float* __restrict__ x, const float* __restrict__ wfg,
                              const float* __restrict__ bgp,
                              int2* __restrict__ rte, float2* __restrict__ rtg,
                              unsigned short* __restrict__ xbf) {
  __shared__ float wfgS[DIM * NEXP];
  const int tid = threadIdx.x;
  for (int i = tid; i < DIM * NEXP; i += 256) wfgS[i] = wfg[i];
  __syncthreads();
  const int w = tid >> 6, lane = tid & 63;
  const size_t t = (size_t)blockIdx.x * 4 + w;
  const float* xr = x + t * DIM;
  unsigned short* xbr = xbf + t * DIM;
  float a0 = 0.f, a1 = 0.f, a2 = 0.f, a3 = 0.f;
#pragma unroll
  for (int i = 0; i < 6; i++) {
    int k = i * 128 + lane * 2;
    float2 xv = *(const float2*)(xr + k);
    ushort2 pk;
    pk.x = f32_to_bf16(xv.x);
    pk.y = f32_to_bf16(xv.y);
    *(ushort2*)(xbr + k) = pk;  // fused convert (saves a 50 MB re-read dispatch)
    a0 += xv.x * wfgS[k * 4 + 0] + xv.y * wfgS[k * 4 + 4];
    a1 += xv.x * wfgS[k * 4 + 1] + xv.y * wfgS[k * 4 + 5];
    a2 += xv.x * wfgS[k * 4 + 2] + xv.y * wfgS[k * 4 + 6];
    a3 += xv.x * wfgS[k * 4 + 3] + xv.y * wfgS[k * 4 + 7];
  }
#pragma unroll
  for (int off = 32; off > 0; off >>= 1) {
    a0 += __shfl_xor(a0, off);
    a1 += __shfl_xor(a1, off);
    a2 += __shfl_xor(a2, off);
    a3 += __shfl_xor(a3, off);
  }
  if (lane == 0) {
    float l[NEXP] = {a0 + bgp[0], a1 + bgp[1], a2 + bgp[2], a3 + bgp[3]};
    float m = fmaxf(fmaxf(l[0], l[1]), fmaxf(l[2], l[3]));
    float p[NEXP]; float s = 0.f;
#pragma unroll
    for (int e = 0; e < NEXP; e++) { p[e] = expf(l[e] - m); s += p[e]; }
#pragma unroll
    for (int e = 0; e < NEXP; e++) p[e] /= s;
    int i1 = 0;
#pragma unroll
    for (int e = 1; e < NEXP; e++) if (p[e] > p[i1]) i1 = e;  // ties -> lowest idx
    int i2 = -1;
#pragma unroll
    for (int e = 0; e < NEXP; e++) { if (e == i1) continue; if (i2 < 0 || p[e] > p[i2]) i2 = e; }
    float denom = p[i1] + p[i2];
    rte[t] = make_int2(i1, i2);
    rtg[t] = make_float2(p[i1] / denom, p[i2] / denom);
  }
}

// ---------- assign: per-expert slot lists + token->slot map ----------
__global__ void assign_kernel(const int2* __restrict__ rte, const float2* __restrict__ rtg,
                              int* __restrict__ cnt, int* __restrict__ idx_tok,
                              float* __restrict__ gate_sel, int2* __restrict__ tok_slot) {
  __shared__ int hist[NEXP];
  __shared__ int base[NEXP];
  const int tid = threadIdx.x;
  if (tid < NEXP) hist[tid] = 0;
  __syncthreads();
  const int t = blockIdx.x * 256 + tid;
  int2 e = rte[t];
  float2 g = rtg[t];
  int r1 = atomicAdd(&hist[e.x], 1);
  int r2 = atomicAdd(&hist[e.y], 1);
  __syncthreads();
  if (tid < NEXP) base[tid] = atomicAdd(&cnt[tid], hist[tid]);
  __syncthreads();
  int s1 = base[e.x] + r1, s2 = base[e.y] + r2;
  idx_tok[e.x * CAP + s1] = t;  gate_sel[e.x * CAP + s1] = g.x;
  idx_tok[e.y * CAP + s2] = t;  gate_sel[e.y * CAP + s2] = g.y;
  tok_slot[t] = make_int2((e.x << 14) | s1, (e.y << 14) | s2);  // packed e|slot
}

// ---------- combine: out[t] = y[row1] + y[row2] + c1*b2[e1] + c2*b2[e2] ----------
// NOTE: tile padding is now 256 rows (256x256 GEMM tiles).
__global__ void combine_kernel(const unsigned short* __restrict__ y,
                               const int2* __restrict__ tok_slot,
                               const float2* __restrict__ rtg,
                               const int* __restrict__ cnts,
                               const float* __restrict__ b2,
                               float* __restrict__ out) {
  __shared__ float b2S[NEXP * DIM];
  const int tid = threadIdx.x;
  for (int i = tid; i < NEXP * DIM; i += 256) b2S[i] = b2[i];
  const int t0 = (cnts[0] + 255) >> 8, t1 = (cnts[1] + 255) >> 8, t2 = (cnts[2] + 255) >> 8;
  const int rb[NEXP] = {0, t0 * 256, (t0 + t1) * 256, (t0 + t1 + t2) * 256};
  __syncthreads();
  const int w = tid >> 6, lane = tid & 63;
  const size_t t = (size_t)blockIdx.x * 4 + w;
  int2 v = tok_slot[t];
  float2 cg = rtg[t];
  const int e1 = v.x >> 14, s1 = v.x & (CAP - 1);
  const int e2 = v.y >> 14, s2 = v.y & (CAP - 1);
  const unsigned short* y1 = y + (size_t)(rb[e1] + s1) * DIM;
  const unsigned short* y2 = y + (size_t)(rb[e2] + s2) * DIM;
  float* op = out + t * DIM;
  const float* bp1 = b2S + e1 * DIM;
  const float* bp2 = b2S + e2 * DIM;
#pragma unroll
  for (int k = 0; k < 12; k++) {
    int n = k * 64 + lane;
    op[n] = bf16_to_f32(y1[n]) + bf16_to_f32(y2[n]) + cg.x * bp1[n] + cg.y * bp2[n];
  }
}

// ---------- bf16 MFMA GEMM: 256x256 tile, BK=64, 8 waves, 8-phase counted-vmcnt ----------
// Structure (learn_hip m201 / T3+T4 template, re-derived for 2-deep buffers):
//  - LDS: A,B each [2 dbuf][2 half][128 rows][64 k] bf16 (128 KiB total), 1 block/CU.
//  - Per K-tile: 4 Gray-ordered quadrant phases (ll, lh, hh, hl). Each phase:
//      {ds_read frag subtile | issue one half-tile stage | s_barrier |
//       setprio(1) 16xMFMA setprio(0) | s_barrier}
//    Register reuse across the Gray walk -> 12/4/8/4 ds_read_b128 per phase.
//  - Stage schedule (tile u): q0: B-lo(u+1), q1: A-hi(u+1), q2: A-lo(u+2), q3: B-hi(u+2).
//    Gate: single `s_waitcnt vmcnt(4)` per K-tile at end of q3 (2 stages = 4 loads
//    stay in flight; all 4 halves of tile u+1 provably retired). Never drains to 0
//    mid-loop -- this is what the old per-iter __syncthreads() (vmcnt(0) drain) cost.
//  - LDS read swizzle: slot ^= (row&7) (16B granule) kills the 16-way conflict of
//    linear [128][64]; inverse swizzle is pre-applied to the per-lane GLOBAL source
//    of global_load_lds (linear LDS dest, rule: both-sides-or-neither).
// MODE 0: dense.  MODE 1: row-gathered A + gelu*gate.  MODE 2: contiguous compacted A.
template <int MODE, int KT>
__launch_bounds__(512, 2)
__global__ void gemm_kernel(const unsigned short* __restrict__ A, const int lda,
                            const unsigned short* __restrict__ Bt, const int ldb,
                            const int N,
                            const float* __restrict__ bias,
                            const int* __restrict__ idx_tok,
                            const float* __restrict__ gate_sel,
                            const int* __restrict__ cnts,
                            unsigned short* __restrict__ outB, const int ldo) {
  int bn = 0, bm0 = 0, bmLoc = 0, cnt = 1 << 30, segBase = 0, gRow0 = 0;

  if constexpr (MODE == 0) {
    const int lin = blockIdx.y * gridDim.x + blockIdx.x;
    const int xcd = lin & 7, t8 = lin >> 3;
    const int nT = gridDim.x;
    bn = t8 % nT;
    const int mc = t8 / nT;
    const int perXcd = gridDim.y >> 3;
    bm0 = (xcd * perXcd + mc) * 256;
  } else {
    const int lin = blockIdx.y * gridDim.x + blockIdx.x;
    const int nT = gridDim.x;
    const int xcd = lin & 7, t8 = lin >> 3;
    const int c0 = cnts[0], c1 = cnts[1], c2 = cnts[2], c3 = cnts[3];
    const int t0 = (c0 + 255) >> 8, t1 = (c1 + 255) >> 8,
              t2 = (c2 + 255) >> 8, t3 = (c3 + 255) >> 8;
    const int p1 = t0, p2 = p1 + t1, p3 = p2 + t2, tot = p3 + t3;
    const int perXcd = (tot + 7) >> 3;  // equal share of ACTIVE tiles per XCD
    bn = t8 % nT;
    const int mloc = t8 / nT;           // n fastest within XCD -> A-panel L2 reuse
    if (mloc >= perXcd) return;
    const int mIdx = xcd * perXcd + mloc;
    if (mIdx >= tot) return;
    const int seg = (mIdx >= p2) ? ((mIdx >= p3) ? 3 : 2) : ((mIdx >= p1) ? 1 : 0);
    const int pre = (seg == 3) ? p3 : (seg == 2) ? p2 : (seg == 1) ? p1 : 0;
    bmLoc = (mIdx - pre) * 256;
    segBase = seg * CAP;
    gRow0 = mIdx * 256;                 // compacted-padded row base = tileIdx*256
    cnt = (seg == 3) ? c3 : (seg == 2) ? c2 : (seg == 1) ? c1 : c0;
    Bt += (size_t)seg * N * ldb;
    if constexpr (MODE == 1) bias += (size_t)seg * N;
  }

  __shared__ unsigned short As[2][2][128 * 64];  // [dbuf][m-half][row][k] 64 KiB
  __shared__ unsigned short Bs[2][2][128 * 64];  // [dbuf][n-half][col][k] 64 KiB
  __shared__ int idxS[256];
  __shared__ float gateS[256];

  const int tid = threadIdx.x;
  const int w8 = tid >> 6;   // wave 0..7
  const int lane = tid & 63;

  if constexpr (MODE == 1) {
    if (tid < 256) {
      int r = bmLoc + tid;
      int cl = (r < cnt) ? r : bmLoc;  // clamp to block's first (valid) row
      idxS[tid] = idx_tok[segBase + cl];
      gateS[tid] = gate_sel[segBase + cl];
    }
    __syncthreads();
  }

  // ---- staging source addresses (per-lane, inverse-swizzled) ----
  // LDS linear pos L = i*8192 + w8*1024 + lane*16 -> row = i*64 + w8*8 + (lane>>3),
  // 16B-slot = lane&7; source slot = (lane&7) ^ (row&7) = (lane&7) ^ (lane>>3).
  const int srow = lane >> 3;
  const int sslot = (lane & 7) ^ srow;
  const unsigned short* aP[2][2];
  const unsigned short* bP[2][2];
#pragma unroll
  for (int h = 0; h < 2; h++)
#pragma unroll
    for (int i = 0; i < 2; i++) {
      const int rr = h * 128 + i * 64 + w8 * 8 + srow;
      size_t arow;
      if constexpr (MODE == 0) arow = (size_t)(bm0 + rr);
      else if constexpr (MODE == 1) arow = (size_t)idxS[rr];
      else arow = (size_t)(gRow0 + rr);
      aP[h][i] = A + arow * lda + sslot * 8;
      bP[h][i] = Bt + (size_t)(bn * 256 + rr) * ldb + sslot * 8;
    }

  // ---- compute-side addressing ----
  const int wr = w8 >> 2, wc = w8 & 3;        // wave grid 2x4 within a quadrant
  const int m16 = lane & 15, q4 = lane >> 4;
  const int rs = m16 & 7;
  const int aBase = (wr * 64 + m16) * 128;    // byte base within A half-buffer
  const int bBase = (wc * 32 + m16) * 128;    // byte base within B half-buffer
  const int s0 = (q4 ^ rs) * 16;              // swizzled 16B slot, kstep 0
  const int s1 = ((4 + q4) ^ rs) * 16;        // swizzled 16B slot, kstep 1

  f32x4 acc[4][4][2];  // [quadrant ll,lh,hl,hh=idx qm*2+qn][m-frag][n-frag]
#pragma unroll
  for (int a_ = 0; a_ < 4; a_++)
#pragma unroll
    for (int b_ = 0; b_ < 4; b_++)
#pragma unroll
      for (int c_ = 0; c_ < 2; c_++) acc[a_][b_][c_] = (f32x4){0.f, 0.f, 0.f, 0.f};
  s16x8 aF[4][2], bF[2][2];

#define BAR()                              \
  {                                        \
    asm volatile("" ::: "memory");         \
    __builtin_amdgcn_s_barrier();          \
    asm volatile("" ::: "memory");         \
  }
#define STAGE_A(bufi, half, kOff)                                                          \
  {                                                                                        \
    char* dA_ = (char*)&As[bufi][half][0] + w8 * 1024;                                     \
    __builtin_amdgcn_global_load_lds(                                                      \
        (const __attribute__((address_space(1))) void*)(aP[half][0] + (kOff)),             \
        (__attribute__((address_space(3))) void*)(dA_), 16, 0, 0);                         \
    __builtin_amdgcn_global_load_lds(                                                      \
        (const __attribute__((address_space(1))) void*)(aP[half][1] + (kOff)),             \
        (__attribute__((address_space(3))) void*)(dA_ + 8192), 16, 0, 0);                  \
  }
#define STAGE_B(bufi, half, kOff)                                                          \
  {                                                                                        \
    char* dB_ = (char*)&Bs[bufi][half][0] + w8 * 1024;                                     \
    __builtin_amdgcn_global_load_lds(                                                      \
        (const __attribute__((address_space(1))) void*)(bP[half][0] + (kOff)),             \
        (__attribute__((address_space(3))) void*)(dB_), 16, 0, 0);                         \
    __builtin_amdgcn_global_load_lds(                                                      \
        (const __attribute__((address_space(1))) void*)(bP[half][1] + (kOff)),             \
        (__attribute__((address_space(3))) void*)(dB_ + 8192), 16, 0, 0);                  \
  }
#define LOAD_A(bufc, qm)                                                 \
  {                                                                      \
    const char* Ah_ = (const char*)&As[bufc][qm][0];                     \
    _Pragma("unroll") for (int fm_ = 0; fm_ < 4; fm_++) {                \
      aF[fm_][0] = *(const s16x8*)(Ah_ + aBase + fm_ * 2048 + s0);       \
      aF[fm_][1] = *(const s16x8*)(Ah_ + aBase + fm_ * 2048 + s1);       \
    }                                                                    \
  }
#define LOAD_B(bufc, qn)                                                 \
  {                                                                      \
    const char* Bh_ = (const char*)&Bs[bufc][qn][0];                     \
    _Pragma("unroll") for (int fn_ = 0; fn_ < 2; fn_++) {                \
      bF[fn_][0] = *(const s16x8*)(Bh_ + bBase + fn_ * 2048 + s0);       \
      bF[fn_][1] = *(const s16x8*)(Bh_ + bBase + fn_ * 2048 + s1);       \
    }                                                                    \
  }
#define MFMA_PH(qi)                                                            \
  {                                                                            \
    __builtin_amdgcn_s_setprio(1);                                             \
    _Pragma("unroll") for (int fm_ = 0; fm_ < 4; fm_++)                        \
    _Pragma("unroll") for (int fn_ = 0; fn_ < 2; fn_++) {                      \
      acc[qi][fm_][fn_] = __builtin_amdgcn_mfma_f32_16x16x32_bf16(             \
          aF[fm_][0], bF[fn_][0], acc[qi][fm_][fn_], 0, 0, 0);                 \
      acc[qi][fm_][fn_] = __builtin_amdgcn_mfma_f32_16x16x32_bf16(             \
          aF[fm_][1], bF[fn_][1], acc[qi][fm_][fn_], 0, 0, 0);                 \
    }                                                                          \
    __builtin_amdgcn_s_setprio(0);                                             \
  }
// One K-tile: Gray quadrant walk (qm,qn) = ll, lh, hh, hl -> acc idx 0,1,3,2.
#define KTILE_BODY(bufc, uu_, DO_S1, DO_S2, VMC4)                        \
  {                                                                      \
    const int kN1_ = ((uu_) + 1) * 64, kN2_ = ((uu_) + 2) * 64;          \
    LOAD_A(bufc, 0); LOAD_B(bufc, 0);                                    \
    if (DO_S1) STAGE_B((bufc) ^ 1, 0, kN1_);                             \
    BAR(); MFMA_PH(0); BAR();                                            \
    LOAD_B(bufc, 1);                                                     \
    if (DO_S1) STAGE_A((bufc) ^ 1, 1, kN1_);                             \
    BAR(); MFMA_PH(1); BAR();                                            \
    LOAD_A(bufc, 1);                                                     \
    if (DO_S2) STAGE_A((bufc), 0, kN2_);                                 \
    BAR(); MFMA_PH(3); BAR();                                            \
    LOAD_B(bufc, 0);                                                     \
    if (DO_S2) STAGE_B((bufc), 1, kN2_);                                 \
    if (VMC4) { asm volatile("s_waitcnt vmcnt(4)" ::: "memory"); }       \
    else      { asm volatile("s_waitcnt vmcnt(0)" ::: "memory"); }       \
    BAR(); MFMA_PH(2); BAR();                                            \
  }

  // prologue: tile 0 complete + tile 1's A-lo/B-hi (loop issues tile 1's B-lo/A-hi)
  STAGE_A(0, 0, 0); STAGE_A(0, 1, 0);
  STAGE_B(0, 0, 0); STAGE_B(0, 1, 0);
  STAGE_A(1, 0, 64); STAGE_B(1, 1, 64);
  asm volatile("s_waitcnt vmcnt(4)" ::: "memory");  // tile 0's 8 loads retired
  BAR();

  static_assert(KT >= 4 && (KT & 1) == 0, "KT must be even, >= 4");
#pragma unroll 1
  for (int uu = 0; uu < (KT - 2) / 2; uu++) {
    KTILE_BODY(0, 2 * uu, 1, 1, 1);
    KTILE_BODY(1, 2 * uu + 1, 1, 1, 1);
  }
  KTILE_BODY(0, KT - 2, 1, 0, 0);  // stages tile KT-1's B-lo/A-hi, then full drain
  KTILE_BODY(1, KT - 1, 0, 0, 0);  // no stages; trailing vmcnt(0) is free

#undef KTILE_BODY
#undef MFMA_PH
#undef LOAD_B
#undef LOAD_A
#undef STAGE_B
#undef STAGE_A
#undef BAR

  // ---- epilogue ----
#pragma unroll
  for (int qi = 0; qi < 4; qi++) {
    const int qm = qi >> 1, qn = qi & 1;
#pragma unroll
    for (int fm = 0; fm < 4; fm++) {
      const int r0 = qm * 128 + wr * 64 + fm * 16 + q4 * 4;
#pragma unroll
      for (int fn = 0; fn < 2; fn++) {
        const int col = bn * 256 + qn * 128 + wc * 32 + fn * 16 + m16;
        if constexpr (MODE == 0) {
          const float bv = bias[col];
#pragma unroll
          for (int r = 0; r < 4; r++)
            outB[(size_t)(bm0 + r0 + r) * ldo + col] = f32_to_bf16(acc[qi][fm][fn][r] + bv);
        } else if constexpr (MODE == 1) {
          const float bv = bias[col];
#pragma unroll
          for (int r = 0; r < 4; r++) {
            const int ro = r0 + r;
            if (bmLoc + ro < cnt) {
              float v = acc[qi][fm][fn][r] + bv;
              float t3 = v + 0.044715f * v * v * v;
              float e2 = exp2f(t3 * 2.302208206984525f);  // e^{2u}, u=sqrt(2/pi)(v+0.044715v^3)
              float rc = __builtin_amdgcn_rcpf(1.0f + e2);
              float gl = v - v * rc;
              outB[(size_t)(gRow0 + ro) * ldo + col] = f32_to_bf16(gl * gateS[ro]);
            }
          }
        } else {
#pragma unroll
          for (int r = 0; r < 4; r++) {
            const int ro = r0 + r;
            if (bmLoc + ro < cnt)
              outB[(size_t)(gRow0 + ro) * ldo + col] = f32_to_bf16(acc[qi][fm][fn][r]);
          }
        }
      }
    }
  }
}

extern "C" void kernel_launch(void* const* d_in, const int* in_sizes, int n_in,
                              void* d_out, int out_size, void* d_ws, size_t ws_size,
                              hipStream_t stream) {
  (void)in_sizes; (void)n_in; (void)out_size; (void)ws_size;
  const float* x  = (const float*)d_in[0];
  const float* W  = (const float*)d_in[1];
  const float* b  = (const float*)d_in[2];
  const float* Wg = (const float*)d_in[3];
  const float* bg = (const float*)d_in[4];
  const float* W1 = (const float*)d_in[5];
  const float* b1 = (const float*)d_in[6];
  const float* W2 = (const float*)d_in[7];
  const float* b2 = (const float*)d_in[8];
  float* out = (float*)d_out;
  char* ws = (char*)d_ws;

  // workspace layout (bytes); xbf/wt alias the g region (dead before g is written)
  unsigned short* tbf  = (unsigned short*)(ws + 0);          // [16384][768] bf16
  unsigned short* w1t  = (unsigned short*)(ws + 25165824);   // [4][1024][768] bf16
  unsigned short* w2t  = (unsigned short*)(ws + 31457280);   // [4][768][1024] bf16
  float* wfg           = (float*)(ws + 37748736);            // [768][4]
  float* bgp           = (float*)(ws + 37761024);            // [4]
  int2*  rte           = (int2*)(ws + 37761280);             // [16384]
  float2* rtg          = (float2*)(ws + 37892352);           // [16384]
  int*   cnt           = (int*)(ws + 38023424);              // [4]
  int*   idx_tok       = (int*)(ws + 38023680);              // [4][CAP]
  float* gate_sel      = (float*)(ws + 38285824);            // [4][CAP]
  int2*  tok_slot      = (int2*)(ws + 38547968);             // [16384]
  unsigned short* g    = (unsigned short*)(ws + 38679040);   // [<=33792][1024] bf16 (compacted, 256-pad)
  unsigned short* xbf  = (unsigned short*)(ws + 38679040);   // alias: [16384][768]
  unsigned short* wt   = (unsigned short*)(ws + 63844864);   // alias: [768][768]
  unsigned short* y    = (unsigned short*)(ws + 107885056);  // [<=33792][768] bf16 (compacted, 256-pad)
  // end: 159,789,568 < ~198 MB proven available

  hipMemsetAsync(cnt, 0, NEXP * sizeof(int), stream);
  transpose_bf16_kernel<<<dim3(24, 24, 1), dim3(32, 8), 0, stream>>>(W, wt, 768, 768, 768, 589824);
  transpose_bf16_kernel<<<dim3(32, 24, 4), dim3(32, 8), 0, stream>>>(W1, w1t, 768, 1024, 768, 786432);
  transpose_bf16_kernel<<<dim3(24, 32, 4), dim3(32, 8), 0, stream>>>(W2, w2t, 1024, 768, 1024, 786432);
  wfg_kernel<<<13, 256, 0, stream>>>(W, Wg, b, bg, wfg, bgp);
  router_kernel<<<4096, 256, 0, stream>>>(x, wfg, bgp, rte, rtg, xbf);  // + fused x->bf16
  assign_kernel<<<64, 256, 0, stream>>>(rte, rtg, cnt, idx_tok, gate_sel, tok_slot);

  // GEMM1: t = bf16(x @ W + b)          [dense, 19.3 GF] 64 m-tiles x 3 n-tiles
  gemm_kernel<0, 12><<<dim3(3, 64), 512, 0, stream>>>(
      xbf, 768, wt, 768, 768, b, nullptr, nullptr, nullptr, tbf, 768);
  // GEMM2: g[row] = bf16(gate * gelu(t[tok] @ W1_e + b1_e))   [gathered, 51.5 GF]
  gemm_kernel<1, 12><<<dim3(4, 136), 512, 0, stream>>>(
      tbf, 768, w1t, 768, 1024, b1, idx_tok, gate_sel, cnt, g, 1024);
  // GEMM3: y[row] = bf16(g[row] @ W2_e)   [write-once, 51.5 GF]
  gemm_kernel<2, 16><<<dim3(3, 136), 512, 0, stream>>>(
      g, 1024, w2t, 1024, 768, nullptr, nullptr, nullptr, cnt, y, 768);
  // combine: out[t] = y[slot1] + y[slot2] + c1*b2[e1] + c2*b2[e2]
  combine_kernel<<<4096, 256, 0, stream>>>(y, tok_slot, rtg, cnt, b2, out);
}

// Round 2
// 423.892 us; speedup vs baseline: 1.0641x; 1.0641x over previous
//
#include <hip/hip_runtime.h>

#define DIM 768
#define NEXP 4
#define DFF_ 1024
#define CAP 16384  // per-expert slot capacity (max possible = T)

typedef __attribute__((ext_vector_type(4))) float f32x4;
typedef __attribute__((ext_vector_type(8))) short s16x8;

__device__ __forceinline__ unsigned short f32_to_bf16(float f) {
  unsigned int u = __float_as_uint(f);
  unsigned int r = (u + 0x7FFFu + ((u >> 16) & 1u)) >> 16;  // RNE
  return (unsigned short)r;
}
__device__ __forceinline__ float bf16_to_f32(unsigned short u) {
  return __uint_as_float(((unsigned int)u) << 16);
}
// generic (__shared__) pointer -> 32-bit LDS byte offset, for asm ds_read vaddr
__device__ __forceinline__ unsigned lds_off(const void* p) {
  return (unsigned)(unsigned long long)(__attribute__((address_space(3))) const void*)p;
}

// ---------- transpose fp32 [R,C] -> bf16, generalized output addressing ----------
__global__ void transpose_bf16_kernel(const float* __restrict__ in,
                                      unsigned short* __restrict__ out,
                                      int R, int C, int ldo, int zOut) {
  __shared__ float tile[32][33];
  const int bx = blockIdx.x, by = blockIdx.y, bz = blockIdx.z;
  in  += (size_t)bz * R * C;
  out += (size_t)bz * zOut;
  const int tx = threadIdx.x, ty = threadIdx.y;
#pragma unroll
  for (int i = 0; i < 4; i++) {
    int r = by * 32 + ty + i * 8;
    int c = bx * 32 + tx;
    tile[ty + i * 8][tx] = in[(size_t)r * C + c];
  }
  __syncthreads();
#pragma unroll
  for (int i = 0; i < 4; i++) {
    int oc = bx * 32 + ty + i * 8;
    int orow = by * 32 + tx;
    out[(size_t)oc * ldo + orow] = f32_to_bf16(tile[tx][ty + i * 8]);
  }
}

// ---------- Wfg = W @ Wg, bgp = b @ Wg + bg (fp32 router weights) ----------
__global__ void wfg_kernel(const float* __restrict__ W, const float* __restrict__ Wg,
                           const float* __restrict__ b, const float* __restrict__ bg,
                           float* __restrict__ wfg, float* __restrict__ bgp) {
  int gid = blockIdx.x * 256 + threadIdx.x;
  if (gid < DIM * NEXP) {
    int k = gid >> 2, e = gid & 3;
    const float* wr = W + (size_t)k * DIM;
    float acc = 0.f;
    for (int d = 0; d < DIM; d++) acc += wr[d] * Wg[d * NEXP + e];
    wfg[gid] = acc;
  } else if (gid < DIM * NEXP + NEXP) {
    int e = gid - DIM * NEXP;
    float acc = bg[e];
    for (int d = 0; d < DIM; d++) acc += b[d] * Wg[d * NEXP + e];
    bgp[e] = acc;
  }
}

// ---------- router (+ fused x->bf16 convert): fp32 logits, softmax, top2 ----------
__global__ void router_kernel(const float* __restrict__ x, const float* __restrict__ wfg,
                              const float* __restrict__ bgp,
                              int2* __restrict__ rte, float2* __restrict__ rtg,
                              unsigned short* __restrict__ xbf) {
  __shared__ float wfgS[DIM * NEXP];
  const int tid = threadIdx.x;
  for (int i = tid; i < DIM * NEXP; i += 256) wfgS[i] = wfg[i];
  __syncthreads();
  const int w = tid >> 6, lane = tid & 63;
  const size_t t = (size_t)blockIdx.x * 4 + w;
  const float* xr = x + t * DIM;
  unsigned short* xbr = xbf + t * DIM;
  float a0 = 0.f, a1 = 0.f, a2 = 0.f, a3 = 0.f;
#pragma unroll
  for (int i = 0; i < 6; i++) {
    int k = i * 128 + lane * 2;
    float2 xv = *(const float2*)(xr + k);
    ushort2 pk;
    pk.x = f32_to_bf16(xv.x);
    pk.y = f32_to_bf16(xv.y);
    *(ushort2*)(xbr + k) = pk;  // fused convert (saves a 50 MB re-read dispatch)
    a0 += xv.x * wfgS[k * 4 + 0] + xv.y * wfgS[k * 4 + 4];
    a1 += xv.x * wfgS[k * 4 + 1] + xv.y * wfgS[k * 4 + 5];
    a2 += xv.x * wfgS[k * 4 + 2] + xv.y * wfgS[k * 4 + 6];
    a3 += xv.x * wfgS[k * 4 + 3] + xv.y * wfgS[k * 4 + 7];
  }
#pragma unroll
  for (int off = 32; off > 0; off >>= 1) {
    a0 += __shfl_xor(a0, off);
    a1 += __shfl_xor(a1, off);
    a2 += __shfl_xor(a2, off);
    a3 += __shfl_xor(a3, off);
  }
  if (lane == 0) {
    float l[NEXP] = {a0 + bgp[0], a1 + bgp[1], a2 + bgp[2], a3 + bgp[3]};
    float m = fmaxf(fmaxf(l[0], l[1]), fmaxf(l[2], l[3]));
    float p[NEXP]; float s = 0.f;
#pragma unroll
    for (int e = 0; e < NEXP; e++) { p[e] = expf(l[e] - m); s += p[e]; }
#pragma unroll
    for (int e = 0; e < NEXP; e++) p[e] /= s;
    int i1 = 0;
#pragma unroll
    for (int e = 1; e < NEXP; e++) if (p[e] > p[i1]) i1 = e;  // ties -> lowest idx
    int i2 = -1;
#pragma unroll
    for (int e = 0; e < NEXP; e++) { if (e == i1) continue; if (i2 < 0 || p[e] > p[i2]) i2 = e; }
    float denom = p[i1] + p[i2];
    rte[t] = make_int2(i1, i2);
    rtg[t] = make_float2(p[i1] / denom, p[i2] / denom);
  }
}

// ---------- assign: per-expert slot lists + token->slot map ----------
__global__ void assign_kernel(const int2* __restrict__ rte, const float2* __restrict__ rtg,
                              int* __restrict__ cnt, int* __restrict__ idx_tok,
                              float* __restrict__ gate_sel, int2* __restrict__ tok_slot) {
  __shared__ int hist[NEXP];
  __shared__ int base[NEXP];
  const int tid = threadIdx.x;
  if (tid < NEXP) hist[tid] = 0;
  __syncthreads();
  const int t = blockIdx.x * 256 + tid;
  int2 e = rte[t];
  float2 g = rtg[t];
  int r1 = atomicAdd(&hist[e.x], 1);
  int r2 = atomicAdd(&hist[e.y], 1);
  __syncthreads();
  if (tid < NEXP) base[tid] = atomicAdd(&cnt[tid], hist[tid]);
  __syncthreads();
  int s1 = base[e.x] + r1, s2 = base[e.y] + r2;
  idx_tok[e.x * CAP + s1] = t;  gate_sel[e.x * CAP + s1] = g.x;
  idx_tok[e.y * CAP + s2] = t;  gate_sel[e.y * CAP + s2] = g.y;
  tok_slot[t] = make_int2((e.x << 14) | s1, (e.y << 14) | s2);  // packed e|slot
}

// ---------- combine: out[t] = y[row1] + y[row2] + c1*b2[e1] + c2*b2[e2] ----------
// NOTE: tile padding is 256 rows (256x256 GEMM tiles).
__global__ void combine_kernel(const unsigned short* __restrict__ y,
                               const int2* __restrict__ tok_slot,
                               const float2* __restrict__ rtg,
                               const int* __restrict__ cnts,
                               const float* __restrict__ b2,
                               float* __restrict__ out) {
  __shared__ float b2S[NEXP * DIM];
  const int tid = threadIdx.x;
  for (int i = tid; i < NEXP * DIM; i += 256) b2S[i] = b2[i];
  const int t0 = (cnts[0] + 255) >> 8, t1 = (cnts[1] + 255) >> 8, t2 = (cnts[2] + 255) >> 8;
  const int rb[NEXP] = {0, t0 * 256, (t0 + t1) * 256, (t0 + t1 + t2) * 256};
  __syncthreads();
  const int w = tid >> 6, lane = tid & 63;
  const size_t t = (size_t)blockIdx.x * 4 + w;
  int2 v = tok_slot[t];
  float2 cg = rtg[t];
  const int e1 = v.x >> 14, s1 = v.x & (CAP - 1);
  const int e2 = v.y >> 14, s2 = v.y & (CAP - 1);
  const unsigned short* y1 = y + (size_t)(rb[e1] + s1) * DIM;
  const unsigned short* y2 = y + (size_t)(rb[e2] + s2) * DIM;
  float* op = out + t * DIM;
  const float* bp1 = b2S + e1 * DIM;
  const float* bp2 = b2S + e2 * DIM;
#pragma unroll
  for (int k = 0; k < 12; k++) {
    int n = k * 64 + lane;
    op[n] = bf16_to_f32(y1[n]) + bf16_to_f32(y2[n]) + cg.x * bp1[n] + cg.y * bp2[n];
  }
}

// ---------- bf16 MFMA GEMM: 256x256 tile, BK=64, 8 waves, 8-phase counted-vmcnt ----------
// R2 change vs R1 (single variable): fragment LDS loads are now inline-asm
// ds_read_b128 instead of compiler-visible C++ loads. R1's counters (MfmaUtil
// 12.5%, ~1700 stall cyc/phase) showed the memory legalizer was inserting
// s_waitcnt vmcnt(0) before each phase's ds_reads (it cannot disambiguate
// As[buf] reads from in-flight global_load_lds DMA writes to As[buf^1]),
// draining the just-issued prefetches every phase. Asm ds_reads are invisible
// to the legalizer; ordering is taken over explicitly per rule 18:
// `s_waitcnt lgkmcnt(0)` + sched_barrier(0) after each pre-MFMA s_barrier.
// Everything else (geometry, stage schedule, vmcnt(4) gate, setprio) == R1.
// MODE 0: dense.  MODE 1: row-gathered A + gelu*gate.  MODE 2: contiguous compacted A.
template <int MODE, int KT>
__launch_bounds__(512, 2)
__global__ void gemm_kernel(const unsigned short* __restrict__ A, const int lda,
                            const unsigned short* __restrict__ Bt, const int ldb,
                            const int N,
                            const float* __restrict__ bias,
                            const int* __restrict__ idx_tok,
                            const float* __restrict__ gate_sel,
                            const int* __restrict__ cnts,
                            unsigned short* __restrict__ outB, const int ldo) {
  int bn = 0, bm0 = 0, bmLoc = 0, cnt = 1 << 30, segBase = 0, gRow0 = 0;

  if constexpr (MODE == 0) {
    const int lin = blockIdx.y * gridDim.x + blockIdx.x;
    const int xcd = lin & 7, t8 = lin >> 3;
    const int nT = gridDim.x;
    bn = t8 % nT;
    const int mc = t8 / nT;
    const int perXcd = gridDim.y >> 3;
    bm0 = (xcd * perXcd + mc) * 256;
  } else {
    const int lin = blockIdx.y * gridDim.x + blockIdx.x;
    const int nT = gridDim.x;
    const int xcd = lin & 7, t8 = lin >> 3;
    const int c0 = cnts[0], c1 = cnts[1], c2 = cnts[2], c3 = cnts[3];
    const int t0 = (c0 + 255) >> 8, t1 = (c1 + 255) >> 8,
              t2 = (c2 + 255) >> 8, t3 = (c3 + 255) >> 8;
    const int p1 = t0, p2 = p1 + t1, p3 = p2 + t2, tot = p3 + t3;
    const int perXcd = (tot + 7) >> 3;  // equal share of ACTIVE tiles per XCD
    bn = t8 % nT;
    const int mloc = t8 / nT;           // n fastest within XCD -> A-panel L2 reuse
    if (mloc >= perXcd) return;
    const int mIdx = xcd * perXcd + mloc;
    if (mIdx >= tot) return;
    const int seg = (mIdx >= p2) ? ((mIdx >= p3) ? 3 : 2) : ((mIdx >= p1) ? 1 : 0);
    const int pre = (seg == 3) ? p3 : (seg == 2) ? p2 : (seg == 1) ? p1 : 0;
    bmLoc = (mIdx - pre) * 256;
    segBase = seg * CAP;
    gRow0 = mIdx * 256;                 // compacted-padded row base = tileIdx*256
    cnt = (seg == 3) ? c3 : (seg == 2) ? c2 : (seg == 1) ? c1 : c0;
    Bt += (size_t)seg * N * ldb;
    if constexpr (MODE == 1) bias += (size_t)seg * N;
  }

  __shared__ unsigned short As[2][2][128 * 64];  // [dbuf][m-half][row][k] 64 KiB
  __shared__ unsigned short Bs[2][2][128 * 64];  // [dbuf][n-half][col][k] 64 KiB
  __shared__ int idxS[256];
  __shared__ float gateS[256];

  const int tid = threadIdx.x;
  const int w8 = tid >> 6;   // wave 0..7
  const int lane = tid & 63;

  if constexpr (MODE == 1) {
    if (tid < 256) {
      int r = bmLoc + tid;
      int cl = (r < cnt) ? r : bmLoc;  // clamp to block's first (valid) row
      idxS[tid] = idx_tok[segBase + cl];
      gateS[tid] = gate_sel[segBase + cl];
    }
    __syncthreads();
  }

  // ---- staging source addresses (per-lane, inverse-swizzled) ----
  // LDS linear pos L = i*8192 + w8*1024 + lane*16 -> row = i*64 + w8*8 + (lane>>3),
  // 16B-slot = lane&7; source slot = (lane&7) ^ (row&7) = (lane&7) ^ (lane>>3).
  const int srow = lane >> 3;
  const int sslot = (lane & 7) ^ srow;
  const unsigned short* aP[2][2];
  const unsigned short* bP[2][2];
#pragma unroll
  for (int h = 0; h < 2; h++)
#pragma unroll
    for (int i = 0; i < 2; i++) {
      const int rr = h * 128 + i * 64 + w8 * 8 + srow;
      size_t arow;
      if constexpr (MODE == 0) arow = (size_t)(bm0 + rr);
      else if constexpr (MODE == 1) arow = (size_t)idxS[rr];
      else arow = (size_t)(gRow0 + rr);
      aP[h][i] = A + arow * lda + sslot * 8;
      bP[h][i] = Bt + (size_t)(bn * 256 + rr) * ldb + sslot * 8;
    }

  // ---- compute-side addressing ----
  const int wr = w8 >> 2, wc = w8 & 3;        // wave grid 2x4 within a quadrant
  const int m16 = lane & 15, q4 = lane >> 4;
  const int rs = m16 & 7;
  const int aBase = (wr * 64 + m16) * 128;    // byte base within A half-buffer
  const int bBase = (wc * 32 + m16) * 128;    // byte base within B half-buffer
  const int s0 = (q4 ^ rs) * 16;              // swizzled 16B slot, kstep 0
  const int s1 = ((4 + q4) ^ rs) * 16;        // swizzled 16B slot, kstep 1

  // per-[buf][half] LDS byte offsets for asm ds_read (all indices literal at use)
  unsigned aO[2][2], bO[2][2];
#pragma unroll
  for (int bf_ = 0; bf_ < 2; bf_++)
#pragma unroll
    for (int hf_ = 0; hf_ < 2; hf_++) {
      aO[bf_][hf_] = lds_off(&As[bf_][hf_][0]) + (unsigned)aBase;
      bO[bf_][hf_] = lds_off(&Bs[bf_][hf_][0]) + (unsigned)bBase;
    }

  f32x4 acc[4][4][2];  // [quadrant ll,lh,hl,hh=idx qm*2+qn][m-frag][n-frag]
#pragma unroll
  for (int a_ = 0; a_ < 4; a_++)
#pragma unroll
    for (int b_ = 0; b_ < 4; b_++)
#pragma unroll
      for (int c_ = 0; c_ < 2; c_++) acc[a_][b_][c_] = (f32x4){0.f, 0.f, 0.f, 0.f};
  s16x8 aF[4][2], bF[2][2];

#define BAR()                              \
  {                                        \
    asm volatile("" ::: "memory");         \
    __builtin_amdgcn_s_barrier();          \
    asm volatile("" ::: "memory");         \
  }
// rule 18: explicit lgkm drain for the asm ds_reads + sched_barrier so MFMA
// cannot be hoisted above the wait by the machine scheduler.
#define WAIT_LGKM()                                        \
  {                                                        \
    asm volatile("s_waitcnt lgkmcnt(0)" ::: "memory");     \
    __builtin_amdgcn_sched_barrier(0);                     \
  }
#define DSR(dst, addr, imm) \
  asm volatile("ds_read_b128 %0, %1 offset:" #imm : "=v"(dst) : "v"(addr))
#define STAGE_A(bufi, half, kOff)                                                          \
  {                                                                                        \
    char* dA_ = (char*)&As[bufi][half][0] + w8 * 1024;                                     \
    __builtin_amdgcn_global_load_lds(                                                      \
        (const __attribute__((address_space(1))) void*)(aP[half][0] + (kOff)),             \
        (__attribute__((address_space(3))) void*)(dA_), 16, 0, 0);                         \
    __builtin_amdgcn_global_load_lds(                                                      \
        (const __attribute__((address_space(1))) void*)(aP[half][1] + (kOff)),             \
        (__attribute__((address_space(3))) void*)(dA_ + 8192), 16, 0, 0);                  \
  }
#define STAGE_B(bufi, half, kOff)                                                          \
  {                                                                                        \
    char* dB_ = (char*)&Bs[bufi][half][0] + w8 * 1024;                                     \
    __builtin_amdgcn_global_load_lds(                                                      \
        (const __attribute__((address_space(1))) void*)(bP[half][0] + (kOff)),             \
        (__attribute__((address_space(3))) void*)(dB_), 16, 0, 0);                         \
    __builtin_amdgcn_global_load_lds(                                                      \
        (const __attribute__((address_space(1))) void*)(bP[half][1] + (kOff)),             \
        (__attribute__((address_space(3))) void*)(dB_ + 8192), 16, 0, 0);                  \
  }
#define LOAD_A(bufc, qm)                                   \
  {                                                        \
    const unsigned a0_ = aO[bufc][qm] + (unsigned)s0;      \
    const unsigned a1_ = aO[bufc][qm] + (unsigned)s1;      \
    DSR(aF[0][0], a0_, 0);    DSR(aF[0][1], a1_, 0);       \
    DSR(aF[1][0], a0_, 2048); DSR(aF[1][1], a1_, 2048);    \
    DSR(aF[2][0], a0_, 4096); DSR(aF[2][1], a1_, 4096);    \
    DSR(aF[3][0], a0_, 6144); DSR(aF[3][1], a1_, 6144);    \
  }
#define LOAD_B(bufc, qn)                                   \
  {                                                        \
    const unsigned b0_ = bO[bufc][qn] + (unsigned)s0;      \
    const unsigned b1_ = bO[bufc][qn] + (unsigned)s1;      \
    DSR(bF[0][0], b0_, 0);    DSR(bF[0][1], b1_, 0);       \
    DSR(bF[1][0], b0_, 2048); DSR(bF[1][1], b1_, 2048);    \
  }
#define MFMA_PH(qi)                                                            \
  {                                                                            \
    __builtin_amdgcn_s_setprio(1);                                             \
    _Pragma("unroll") for (int fm_ = 0; fm_ < 4; fm_++)                        \
    _Pragma("unroll") for (int fn_ = 0; fn_ < 2; fn_++) {                      \
      acc[qi][fm_][fn_] = __builtin_amdgcn_mfma_f32_16x16x32_bf16(             \
          aF[fm_][0], bF[fn_][0], acc[qi][fm_][fn_], 0, 0, 0);                 \
      acc[qi][fm_][fn_] = __builtin_amdgcn_mfma_f32_16x16x32_bf16(             \
          aF[fm_][1], bF[fn_][1], acc[qi][fm_][fn_], 0, 0, 0);                 \
    }                                                                          \
    __builtin_amdgcn_s_setprio(0);                                             \
  }
// One K-tile: Gray quadrant walk (qm,qn) = ll, lh, hh, hl -> acc idx 0,1,3,2.
// Stage schedule (tile u): ph0: B-lo(u+1), ph1: A-hi(u+1), ph2: A-lo(u+2),
// ph3: B-hi(u+2); single vmcnt(4) gate at tile end (2 stages stay in flight).
#define KTILE_BODY(bufc, uu_, DO_S1, DO_S2, VMC4)                        \
  {                                                                      \
    const int kN1_ = ((uu_) + 1) * 64, kN2_ = ((uu_) + 2) * 64;          \
    LOAD_A(bufc, 0); LOAD_B(bufc, 0);                                    \
    if (DO_S1) STAGE_B((bufc) ^ 1, 0, kN1_);                             \
    BAR(); WAIT_LGKM(); MFMA_PH(0); BAR();                               \
    LOAD_B(bufc, 1);                                                     \
    if (DO_S1) STAGE_A((bufc) ^ 1, 1, kN1_);                             \
    BAR(); WAIT_LGKM(); MFMA_PH(1); BAR();                               \
    LOAD_A(bufc, 1);                                                     \
    if (DO_S2) STAGE_A((bufc), 0, kN2_);                                 \
    BAR(); WAIT_LGKM(); MFMA_PH(3); BAR();                               \
    LOAD_B(bufc, 0);                                                     \
    if (DO_S2) STAGE_B((bufc), 1, kN2_);                                 \
    if (VMC4) { asm volatile("s_waitcnt vmcnt(4)" ::: "memory"); }       \
    else      { asm volatile("s_waitcnt vmcnt(0)" ::: "memory"); }       \
    BAR(); WAIT_LGKM(); MFMA_PH(2); BAR();                               \
  }

  // prologue: tile 0 complete + tile 1's A-lo/B-hi (loop issues tile 1's B-lo/A-hi)
  STAGE_A(0, 0, 0); STAGE_A(0, 1, 0);
  STAGE_B(0, 0, 0); STAGE_B(0, 1, 0);
  STAGE_A(1, 0, 64); STAGE_B(1, 1, 64);
  asm volatile("s_waitcnt vmcnt(4)" ::: "memory");  // tile 0's 8 loads retired
  BAR();

  static_assert(KT >= 4 && (KT & 1) == 0, "KT must be even, >= 4");
#pragma unroll 1
  for (int uu = 0; uu < (KT - 2) / 2; uu++) {
    KTILE_BODY(0, 2 * uu, 1, 1, 1);
    KTILE_BODY(1, 2 * uu + 1, 1, 1, 1);
  }
  KTILE_BODY(0, KT - 2, 1, 0, 0);  // stages tile KT-1's B-lo/A-hi, then full drain
  KTILE_BODY(1, KT - 1, 0, 0, 0);  // no stages; trailing vmcnt(0) is free

#undef KTILE_BODY
#undef MFMA_PH
#undef LOAD_B
#undef LOAD_A
#undef STAGE_B
#undef STAGE_A
#undef DSR
#undef WAIT_LGKM
#undef BAR

  // ---- epilogue ----
#pragma unroll
  for (int qi = 0; qi < 4; qi++) {
    const int qm = qi >> 1, qn = qi & 1;
#pragma unroll
    for (int fm = 0; fm < 4; fm++) {
      const int r0 = qm * 128 + wr * 64 + fm * 16 + q4 * 4;
#pragma unroll
      for (int fn = 0; fn < 2; fn++) {
        const int col = bn * 256 + qn * 128 + wc * 32 + fn * 16 + m16;
        if constexpr (MODE == 0) {
          const float bv = bias[col];
#pragma unroll
          for (int r = 0; r < 4; r++)
            outB[(size_t)(bm0 + r0 + r) * ldo + col] = f32_to_bf16(acc[qi][fm][fn][r] + bv);
        } else if constexpr (MODE == 1) {
          const float bv = bias[col];
#pragma unroll
          for (int r = 0; r < 4; r++) {
            const int ro = r0 + r;
            if (bmLoc + ro < cnt) {
              float v = acc[qi][fm][fn][r] + bv;
              float t3 = v + 0.044715f * v * v * v;
              float e2 = exp2f(t3 * 2.302208206984525f);  // e^{2u}, u=sqrt(2/pi)(v+0.044715v^3)
              float rc = __builtin_amdgcn_rcpf(1.0f + e2);
              float gl = v - v * rc;
              outB[(size_t)(gRow0 + ro) * ldo + col] = f32_to_bf16(gl * gateS[ro]);
            }
          }
        } else {
#pragma unroll
          for (int r = 0; r < 4; r++) {
            const int ro = r0 + r;
            if (bmLoc + ro < cnt)
              outB[(size_t)(gRow0 + ro) * ldo + col] = f32_to_bf16(acc[qi][fm][fn][r]);
          }
        }
      }
    }
  }
}

extern "C" void kernel_launch(void* const* d_in, const int* in_sizes, int n_in,
                              void* d_out, int out_size, void* d_ws, size_t ws_size,
                              hipStream_t stream) {
  (void)in_sizes; (void)n_in; (void)out_size; (void)ws_size;
  const float* x  = (const float*)d_in[0];
  const float* W  = (const float*)d_in[1];
  const float* b  = (const float*)d_in[2];
  const float* Wg = (const float*)d_in[3];
  const float* bg = (const float*)d_in[4];
  const float* W1 = (const float*)d_in[5];
  const float* b1 = (const float*)d_in[6];
  const float* W2 = (const float*)d_in[7];
  const float* b2 = (const float*)d_in[8];
  float* out = (float*)d_out;
  char* ws = (char*)d_ws;

  // workspace layout (bytes); xbf/wt alias the g region (dead before g is written)
  unsigned short* tbf  = (unsigned short*)(ws + 0);          // [16384][768] bf16
  unsigned short* w1t  = (unsigned short*)(ws + 25165824);   // [4][1024][768] bf16
  unsigned short* w2t  = (unsigned short*)(ws + 31457280);   // [4][768][1024] bf16
  float* wfg           = (float*)(ws + 37748736);            // [768][4]
  float* bgp           = (float*)(ws + 37761024);            // [4]
  int2*  rte           = (int2*)(ws + 37761280);             // [16384]
  float2* rtg          = (float2*)(ws + 37892352);           // [16384]
  int*   cnt           = (int*)(ws + 38023424);              // [4]
  int*   idx_tok       = (int*)(ws + 38023680);              // [4][CAP]
  float* gate_sel      = (float*)(ws + 38285824);            // [4][CAP]
  int2*  tok_slot      = (int2*)(ws + 38547968);             // [16384]
  unsigned short* g    = (unsigned short*)(ws + 38679040);   // [<=33792][1024] bf16 (compacted, 256-pad)
  unsigned short* xbf  = (unsigned short*)(ws + 38679040);   // alias: [16384][768]
  unsigned short* wt   = (unsigned short*)(ws + 63844864);   // alias: [768][768]
  unsigned short* y    = (unsigned short*)(ws + 107885056);  // [<=33792][768] bf16 (compacted, 256-pad)
  // end: 159,789,568 < ~198 MB proven available

  hipMemsetAsync(cnt, 0, NEXP * sizeof(int), stream);
  transpose_bf16_kernel<<<dim3(24, 24, 1), dim3(32, 8), 0, stream>>>(W, wt, 768, 768, 768, 589824);
  transpose_bf16_kernel<<<dim3(32, 24, 4), dim3(32, 8), 0, stream>>>(W1, w1t, 768, 1024, 768, 786432);
  transpose_bf16_kernel<<<dim3(24, 32, 4), dim3(32, 8), 0, stream>>>(W2, w2t, 1024, 768, 1024, 786432);
  wfg_kernel<<<13, 256, 0, stream>>>(W, Wg, b, bg, wfg, bgp);
  router_kernel<<<4096, 256, 0, stream>>>(x, wfg, bgp, rte, rtg, xbf);  // + fused x->bf16
  assign_kernel<<<64, 256, 0, stream>>>(rte, rtg, cnt, idx_tok, gate_sel, tok_slot);

  // GEMM1: t = bf16(x @ W + b)          [dense, 19.3 GF] 64 m-tiles x 3 n-tiles
  gemm_kernel<0, 12><<<dim3(3, 64), 512, 0, stream>>>(
      xbf, 768, wt, 768, 768, b, nullptr, nullptr, nullptr, tbf, 768);
  // GEMM2: g[row] = bf16(gate * gelu(t[tok] @ W1_e + b1_e))   [gathered, 51.5 GF]
  gemm_kernel<1, 12><<<dim3(4, 136), 512, 0, stream>>>(
      tbf, 768, w1t, 768, 1024, b1, idx_tok, gate_sel, cnt, g, 1024);
  // GEMM3: y[row] = bf16(g[row] @ W2_e)   [write-once, 51.5 GF]
  gemm_kernel<2, 16><<<dim3(3, 136), 512, 0, stream>>>(
      g, 1024, w2t, 1024, 768, nullptr, nullptr, nullptr, cnt, y, 768);
  // combine: out[t] = y[slot1] + y[slot2] + c1*b2[e1] + c2*b2[e2]
  combine_kernel<<<4096, 256, 0, stream>>>(y, tok_slot, rtg, cnt, b2, out);
}

// Round 4
// 397.612 us; speedup vs baseline: 1.1344x; 1.0661x over previous
//
#include <hip/hip_runtime.h>

#define DIM 768
#define NEXP 4
#define DFF_ 1024
#define CAP 16384  // per-expert slot capacity (max possible = T)

typedef __attribute__((ext_vector_type(4))) float f32x4;
typedef __attribute__((ext_vector_type(8))) short s16x8;

__device__ __forceinline__ unsigned short f32_to_bf16(float f) {
  unsigned int u = __float_as_uint(f);
  unsigned int r = (u + 0x7FFFu + ((u >> 16) & 1u)) >> 16;  // RNE
  return (unsigned short)r;
}
__device__ __forceinline__ float bf16_to_f32(unsigned short u) {
  return __uint_as_float(((unsigned int)u) << 16);
}
// generic (__shared__) pointer -> 32-bit LDS byte offset, for asm ds_read vaddr
__device__ __forceinline__ unsigned lds_off(const void* p) {
  return (unsigned)(unsigned long long)(__attribute__((address_space(3))) const void*)p;
}

// ---------- transpose fp32 [R,C] -> bf16, generalized output addressing ----------
__global__ void transpose_bf16_kernel(const float* __restrict__ in,
                                      unsigned short* __restrict__ out,
                                      int R, int C, int ldo, int zOut) {
  __shared__ float tile[32][33];
  const int bx = blockIdx.x, by = blockIdx.y, bz = blockIdx.z;
  in  += (size_t)bz * R * C;
  out += (size_t)bz * zOut;
  const int tx = threadIdx.x, ty = threadIdx.y;
#pragma unroll
  for (int i = 0; i < 4; i++) {
    int r = by * 32 + ty + i * 8;
    int c = bx * 32 + tx;
    tile[ty + i * 8][tx] = in[(size_t)r * C + c];
  }
  __syncthreads();
#pragma unroll
  for (int i = 0; i < 4; i++) {
    int oc = bx * 32 + ty + i * 8;
    int orow = by * 32 + tx;
    out[(size_t)oc * ldo + orow] = f32_to_bf16(tile[tx][ty + i * 8]);
  }
}

// ---------- Wfg = W @ Wg, bgp = b @ Wg + bg (fp32 router weights) ----------
__global__ void wfg_kernel(const float* __restrict__ W, const float* __restrict__ Wg,
                           const float* __restrict__ b, const float* __restrict__ bg,
                           float* __restrict__ wfg, float* __restrict__ bgp) {
  int gid = blockIdx.x * 256 + threadIdx.x;
  if (gid < DIM * NEXP) {
    int k = gid >> 2, e = gid & 3;
    const float* wr = W + (size_t)k * DIM;
    float acc = 0.f;
    for (int d = 0; d < DIM; d++) acc += wr[d] * Wg[d * NEXP + e];
    wfg[gid] = acc;
  } else if (gid < DIM * NEXP + NEXP) {
    int e = gid - DIM * NEXP;
    float acc = bg[e];
    for (int d = 0; d < DIM; d++) acc += b[d] * Wg[d * NEXP + e];
    bgp[e] = acc;
  }
}

// ---------- router (+ fused x->bf16 convert): fp32 logits, softmax, top2 ----------
__global__ void router_kernel(const float* __restrict__ x, const float* __restrict__ wfg,
                              const float* __restrict__ bgp,
                              int2* __restrict__ rte, float2* __restrict__ rtg,
                              unsigned short* __restrict__ xbf) {
  __shared__ float wfgS[DIM * NEXP];
  const int tid = threadIdx.x;
  for (int i = tid; i < DIM * NEXP; i += 256) wfgS[i] = wfg[i];
  __syncthreads();
  const int w = tid >> 6, lane = tid & 63;
  const size_t t = (size_t)blockIdx.x * 4 + w;
  const float* xr = x + t * DIM;
  unsigned short* xbr = xbf + t * DIM;
  float a0 = 0.f, a1 = 0.f, a2 = 0.f, a3 = 0.f;
#pragma unroll
  for (int i = 0; i < 6; i++) {
    int k = i * 128 + lane * 2;
    float2 xv = *(const float2*)(xr + k);
    ushort2 pk;
    pk.x = f32_to_bf16(xv.x);
    pk.y = f32_to_bf16(xv.y);
    *(ushort2*)(xbr + k) = pk;  // fused convert (saves a 50 MB re-read dispatch)
    a0 += xv.x * wfgS[k * 4 + 0] + xv.y * wfgS[k * 4 + 4];
    a1 += xv.x * wfgS[k * 4 + 1] + xv.y * wfgS[k * 4 + 5];
    a2 += xv.x * wfgS[k * 4 + 2] + xv.y * wfgS[k * 4 + 6];
    a3 += xv.x * wfgS[k * 4 + 3] + xv.y * wfgS[k * 4 + 7];
  }
#pragma unroll
  for (int off = 32; off > 0; off >>= 1) {
    a0 += __shfl_xor(a0, off);
    a1 += __shfl_xor(a1, off);
    a2 += __shfl_xor(a2, off);
    a3 += __shfl_xor(a3, off);
  }
  if (lane == 0) {
    float l[NEXP] = {a0 + bgp[0], a1 + bgp[1], a2 + bgp[2], a3 + bgp[3]};
    float m = fmaxf(fmaxf(l[0], l[1]), fmaxf(l[2], l[3]));
    float p[NEXP]; float s = 0.f;
#pragma unroll
    for (int e = 0; e < NEXP; e++) { p[e] = expf(l[e] - m); s += p[e]; }
#pragma unroll
    for (int e = 0; e < NEXP; e++) p[e] /= s;
    int i1 = 0;
#pragma unroll
    for (int e = 1; e < NEXP; e++) if (p[e] > p[i1]) i1 = e;  // ties -> lowest idx
    int i2 = -1;
#pragma unroll
    for (int e = 0; e < NEXP; e++) { if (e == i1) continue; if (i2 < 0 || p[e] > p[i2]) i2 = e; }
    float denom = p[i1] + p[i2];
    rte[t] = make_int2(i1, i2);
    rtg[t] = make_float2(p[i1] / denom, p[i2] / denom);
  }
}

// ---------- assign: per-expert slot lists + token->slot map ----------
__global__ void assign_kernel(const int2* __restrict__ rte, const float2* __restrict__ rtg,
                              int* __restrict__ cnt, int* __restrict__ idx_tok,
                              float* __restrict__ gate_sel, int2* __restrict__ tok_slot) {
  __shared__ int hist[NEXP];
  __shared__ int base[NEXP];
  const int tid = threadIdx.x;
  if (tid < NEXP) hist[tid] = 0;
  __syncthreads();
  const int t = blockIdx.x * 256 + tid;
  int2 e = rte[t];
  float2 g = rtg[t];
  int r1 = atomicAdd(&hist[e.x], 1);
  int r2 = atomicAdd(&hist[e.y], 1);
  __syncthreads();
  if (tid < NEXP) base[tid] = atomicAdd(&cnt[tid], hist[tid]);
  __syncthreads();
  int s1 = base[e.x] + r1, s2 = base[e.y] + r2;
  idx_tok[e.x * CAP + s1] = t;  gate_sel[e.x * CAP + s1] = g.x;
  idx_tok[e.y * CAP + s2] = t;  gate_sel[e.y * CAP + s2] = g.y;
  tok_slot[t] = make_int2((e.x << 14) | s1, (e.y << 14) | s2);  // packed e|slot
}

// ---------- combine: out[t] = y[row1] + y[row2] + c1*b2[e1] + c2*b2[e2] ----------
__global__ void combine_kernel(const unsigned short* __restrict__ y,
                               const int2* __restrict__ tok_slot,
                               const float2* __restrict__ rtg,
                               const int* __restrict__ cnts,
                               const float* __restrict__ b2,
                               float* __restrict__ out) {
  __shared__ float b2S[NEXP * DIM];
  const int tid = threadIdx.x;
  for (int i = tid; i < NEXP * DIM; i += 256) b2S[i] = b2[i];
  const int t0 = (cnts[0] + 127) >> 7, t1 = (cnts[1] + 127) >> 7, t2 = (cnts[2] + 127) >> 7;
  const int rb[NEXP] = {0, t0 * 128, (t0 + t1) * 128, (t0 + t1 + t2) * 128};
  __syncthreads();
  const int w = tid >> 6, lane = tid & 63;
  const size_t t = (size_t)blockIdx.x * 4 + w;
  int2 v = tok_slot[t];
  float2 cg = rtg[t];
  const int e1 = v.x >> 14, s1 = v.x & (CAP - 1);
  const int e2 = v.y >> 14, s2 = v.y & (CAP - 1);
  const unsigned short* y1 = y + (size_t)(rb[e1] + s1) * DIM;
  const unsigned short* y2 = y + (size_t)(rb[e2] + s2) * DIM;
  float* op = out + t * DIM;
  const float* bp1 = b2S + e1 * DIM;
  const float* bp2 = b2S + e2 * DIM;
#pragma unroll
  for (int k = 0; k < 12; k++) {
    int n = k * 64 + lane;
    op[n] = bf16_to_f32(y1[n]) + bf16_to_f32(y2[n]) + cg.x * bp1[n] + cg.y * bp2[n];
  }
}

// ---------- bf16 MFMA GEMM: 128x128 tile, TRIPLE-buffered, counted-vmcnt K-loop ----------
// R4 = R3 + launch-site fix (GEMM3 N=768, was 1024 -> read past w2t -> NaN).
// Structure under test (unchanged from R3): R0's proven 128^2 geometry
// (2-3 blocks/CU, fine-grained grid) with its one measured stall removed:
// R0 issued stage k+1 then the next __syncthreads() drained vmcnt(0) ~350cy
// later -- ~500cy of the ~900cy HBM latency exposed per K-step. Now: 3 LDS
// buffers, stage issued 2 tiles ahead, gate is a counted `s_waitcnt vmcnt(8)`
// (8 newer loads stay in flight; exactly tile i's 4 retire), and both barriers
// are raw s_barrier with NO vmem drain.
// Hazard ledger: reads of buf[i%3] happen after gate+BAR1 (all waves' slices
// landed); buf[i%3] is re-staged by ISSUEs at iter i+1, which every wave issues
// only after BAR2(i), and every wave completed its reads (lgkmcnt(0)) before
// arriving at BAR2(i). Tail peeled: gate vmcnt(4) then vmcnt(0). Epilogue
// bias loads can't hoist across the gates (asm "memory" clobbers), so the
// vmcnt ledger is exact. Asm ds_read_b128 (R2-proven) keeps the memory
// legalizer from injecting vmcnt(0) before the fragment reads; rule-18 fence
// after lgkmcnt(0).
// MODE 0: dense. MODE 1: row-gathered A + gelu*gate. MODE 2: contiguous A.
template <int MODE, int CH, int NT>
__launch_bounds__(256, 3)
__global__ void gemm_kernel(const unsigned short* __restrict__ A, const int lda,
                            const unsigned short* __restrict__ Bt, const int ldb,
                            const int N,
                            const float* __restrict__ bias,
                            const int* __restrict__ idx_tok,
                            const float* __restrict__ gate_sel,
                            const int* __restrict__ cnts,
                            unsigned short* __restrict__ outB, const int ldo) {
  const int lin = blockIdx.y * gridDim.x + blockIdx.x;
  const int nT = gridDim.x;
  const int xcd = lin & 7, t8 = lin >> 3;
  int bn = 0, bm0 = 0;
  int bmLoc = 0, cnt = 1 << 30, segBase = 0, gRow0 = 0;

  if constexpr (MODE == 0) {
    const int perXcd = gridDim.y >> 3;
    const int mi = t8 % CH;
    const int rest = t8 / CH;
    bn = rest % nT;
    const int mc = rest / nT;
    bm0 = (xcd * perXcd + mc * CH + mi) * 128;
  } else {
    const int c0 = cnts[0], c1 = cnts[1], c2 = cnts[2], c3 = cnts[3];
    const int t0 = (c0 + 127) >> 7, t1 = (c1 + 127) >> 7,
              t2 = (c2 + 127) >> 7, t3 = (c3 + 127) >> 7;
    const int p1 = t0, p2 = p1 + t1, p3 = p2 + t2, tot = p3 + t3;
    const int perXcd = (tot + 7) >> 3;  // equal share of ACTIVE tiles per XCD
    bn = t8 % nT;
    const int mloc = t8 / nT;           // n fastest within XCD -> A-tile L2 reuse
    if (mloc >= perXcd) return;
    const int mIdx = xcd * perXcd + mloc;
    if (mIdx >= tot) return;
    const int seg = (mIdx >= p2) ? ((mIdx >= p3) ? 3 : 2) : ((mIdx >= p1) ? 1 : 0);
    const int pre = (seg == 3) ? p3 : (seg == 2) ? p2 : (seg == 1) ? p1 : 0;
    bmLoc = (mIdx - pre) * 128;
    segBase = seg * CAP;
    gRow0 = mIdx * 128;                 // compacted-padded row base = tileIdx*128
    cnt = (seg == 3) ? c3 : (seg == 2) ? c2 : (seg == 1) ? c1 : c0;
    Bt += (size_t)seg * N * ldb;
    if constexpr (MODE == 1) bias += (size_t)seg * N;
  }

  __shared__ unsigned short As[3][128 * 32];  // 24 KiB (3 bufs)
  __shared__ unsigned short Bs[3][128 * 32];  // 24 KiB
  __shared__ int idxS[128];
  __shared__ float gateS[128];

  const int tid = threadIdx.x;
  const int w = tid >> 6;
  const int lane = tid & 63;

  if constexpr (MODE == 1) {
    if (tid < 128) {
      int r = bmLoc + tid;
      int cl = (r < cnt) ? r : bmLoc;  // clamp to block's first (valid) row
      idxS[tid] = idx_tok[segBase + cl];
      gateS[tid] = gate_sel[segBase + cl];
    }
    __syncthreads();
  }

  // per-thread staging rows are constant across K
  const int r0 = tid >> 2, r1 = 64 + r0;
  const int gq = (tid & 3) ^ (r0 & 3);  // quad XOR swizzle (r1&3 == r0&3)
  const unsigned short *aP0, *aP1;
  if constexpr (MODE == 0) {
    aP0 = A + (size_t)(bm0 + r0) * lda + gq * 8;
    aP1 = A + (size_t)(bm0 + r1) * lda + gq * 8;
  } else if constexpr (MODE == 1) {
    aP0 = A + (size_t)idxS[r0] * lda + gq * 8;
    aP1 = A + (size_t)idxS[r1] * lda + gq * 8;
  } else {
    aP0 = A + (size_t)(gRow0 + r0) * lda + gq * 8;  // contiguous compacted rows
    aP1 = A + (size_t)(gRow0 + r1) * lda + gq * 8;
  }
  const unsigned short* bP0 = Bt + (size_t)(bn * 128 + r0) * ldb + gq * 8;
  const unsigned short* bP1 = Bt + (size_t)(bn * 128 + r1) * ldb + gq * 8;

  const int quad = lane >> 4;
  const int m16 = lane & 15;
  const int wm = (w & 1) * 64;
  const int wn = (w >> 1) * 64;
  const int sw = (quad ^ (m16 & 3)) * 16;  // de-swizzle

  const unsigned aBase0 = lds_off(&As[0][0]);
  const unsigned bBase0 = lds_off(&Bs[0][0]);
  const unsigned aRd = (unsigned)((wm + m16) * 64 + sw);
  const unsigned bRd = (unsigned)((wn + m16) * 64 + sw);

  f32x4 acc[4][4];
#pragma unroll
  for (int i = 0; i < 4; i++)
#pragma unroll
    for (int j = 0; j < 4; j++) acc[i][j] = (f32x4){0.f, 0.f, 0.f, 0.f};

#define GLL(src, dst)                                                              \
  __builtin_amdgcn_global_load_lds((const __attribute__((address_space(1))) void*)(src), \
                                   (__attribute__((address_space(3))) void*)(dst), 16, 0, 0)
#define ISSUE(off, kk)                                                   \
  {                                                                      \
    char* la0 = (char*)&As[0][0] + (off) + w * 1024;                     \
    char* lb0 = (char*)&Bs[0][0] + (off) + w * 1024;                     \
    GLL(aP0 + (kk), la0);                                                \
    GLL(aP1 + (kk), la0 + 4096);                                         \
    GLL(bP0 + (kk), lb0);                                                \
    GLL(bP1 + (kk), lb0 + 4096);                                         \
  }
#define DSR(dst, addr, imm) \
  asm volatile("ds_read_b128 %0, %1 offset:" #imm : "=v"(dst) : "v"(addr))
// One K-step: gate own DMA queue (counted), sync, asm-read frags, sync (frees
// cur buf for next iter's ISSUE), MFMA. Neither barrier drains vmem.
#define KSTEP(GATE)                                                          \
  {                                                                          \
    asm volatile("s_waitcnt vmcnt(" #GATE ")" ::: "memory");                 \
    __builtin_amdgcn_s_barrier();                                            \
    asm volatile("" ::: "memory");                                           \
    s16x8 af[4], bf4[4];                                                     \
    const unsigned aAd = aBase0 + curOff + aRd;                              \
    const unsigned bAd = bBase0 + curOff + bRd;                              \
    DSR(af[0], aAd, 0);                                                      \
    DSR(af[1], aAd, 1024);                                                   \
    DSR(af[2], aAd, 2048);                                                   \
    DSR(af[3], aAd, 3072);                                                   \
    DSR(bf4[0], bAd, 0);                                                     \
    DSR(bf4[1], bAd, 1024);                                                  \
    DSR(bf4[2], bAd, 2048);                                                  \
    DSR(bf4[3], bAd, 3072);                                                  \
    asm volatile("s_waitcnt lgkmcnt(0)" ::: "memory");                       \
    __builtin_amdgcn_sched_barrier(0);                                       \
    __builtin_amdgcn_s_barrier();                                            \
    asm volatile("" ::: "memory");                                           \
    __builtin_amdgcn_s_setprio(1);                                           \
    _Pragma("unroll") for (int i_ = 0; i_ < 4; i_++)                         \
    _Pragma("unroll") for (int j_ = 0; j_ < 4; j_++)                         \
      acc[i_][j_] = __builtin_amdgcn_mfma_f32_16x16x32_bf16(af[i_], bf4[j_], \
                                                            acc[i_][j_], 0, 0, 0); \
    __builtin_amdgcn_s_setprio(0);                                           \
    curOff = (curOff == 16384u) ? 0u : curOff + 8192u;                       \
  }

  // prologue: tiles 0 and 1 in flight before first gate
  ISSUE(0, 0);
  ISSUE(8192, 32);
  unsigned curOff = 0;       // byte offset of buffer being computed
  unsigned stOff = 16384;    // byte offset of stage target (tile i+2)
  int kk = 64;               // element-k of stage target

  static_assert(NT >= 3, "NT must be >= 3");
#pragma unroll 1
  for (int i = 0; i < NT - 2; ++i) {
    ISSUE(stOff, kk);
    kk += 32;
    stOff = (stOff == 16384u) ? 0u : stOff + 8192u;
    KSTEP(8);   // 8 newer loads (tiles i+1, i+2) stay in flight
  }
  KSTEP(4);     // tile NT-2: only tile NT-1's 4 loads remain in flight
  KSTEP(0);     // tile NT-1: drain (tail, free)

#undef KSTEP
#undef DSR
#undef ISSUE
#undef GLL

#pragma unroll
  for (int i = 0; i < 4; i++) {
    const int rloc = wm + i * 16 + quad * 4;
#pragma unroll
    for (int j = 0; j < 4; j++) {
      const int col = bn * 128 + wn + j * 16 + m16;
      if constexpr (MODE == 0) {
        float bv = bias[col];
#pragma unroll
        for (int r = 0; r < 4; r++)
          outB[(size_t)(bm0 + rloc + r) * ldo + col] = f32_to_bf16(acc[i][j][r] + bv);
      } else if constexpr (MODE == 1) {
        float bv = bias[col];
#pragma unroll
        for (int r = 0; r < 4; r++) {
          if (bmLoc + rloc + r < cnt) {
            float v = acc[i][j][r] + bv;
            float t3 = v + 0.044715f * v * v * v;
            float e2 = exp2f(t3 * 2.302208206984525f);  // e^{2u}, u=sqrt(2/pi)(v+0.044715v^3)
            float rc = __builtin_amdgcn_rcpf(1.0f + e2);
            float g = v - v * rc;
            outB[(size_t)(gRow0 + rloc + r) * ldo + col] = f32_to_bf16(g * gateS[rloc + r]);
          }
        }
      } else {
#pragma unroll
        for (int r = 0; r < 4; r++) {
          if (bmLoc + rloc + r < cnt)
            outB[(size_t)(gRow0 + rloc + r) * ldo + col] = f32_to_bf16(acc[i][j][r]);
        }
      }
    }
  }
}

extern "C" void kernel_launch(void* const* d_in, const int* in_sizes, int n_in,
                              void* d_out, int out_size, void* d_ws, size_t ws_size,
                              hipStream_t stream) {
  (void)in_sizes; (void)n_in; (void)out_size; (void)ws_size;
  const float* x  = (const float*)d_in[0];
  const float* W  = (const float*)d_in[1];
  const float* b  = (const float*)d_in[2];
  const float* Wg = (const float*)d_in[3];
  const float* bg = (const float*)d_in[4];
  const float* W1 = (const float*)d_in[5];
  const float* b1 = (const float*)d_in[6];
  const float* W2 = (const float*)d_in[7];
  const float* b2 = (const float*)d_in[8];
  float* out = (float*)d_out;
  char* ws = (char*)d_ws;

  // workspace layout (bytes); xbf/wt alias the g region (dead before g is written)
  unsigned short* tbf  = (unsigned short*)(ws + 0);          // [16384][768] bf16
  unsigned short* w1t  = (unsigned short*)(ws + 25165824);   // [4][1024][768] bf16
  unsigned short* w2t  = (unsigned short*)(ws + 31457280);   // [4][768][1024] bf16
  float* wfg           = (float*)(ws + 37748736);            // [768][4]
  float* bgp           = (float*)(ws + 37761024);            // [4]
  int2*  rte           = (int2*)(ws + 37761280);             // [16384]
  float2* rtg          = (float2*)(ws + 37892352);           // [16384]
  int*   cnt           = (int*)(ws + 38023424);              // [4]
  int*   idx_tok       = (int*)(ws + 38023680);              // [4][CAP]
  float* gate_sel      = (float*)(ws + 38285824);            // [4][CAP]
  int2*  tok_slot      = (int2*)(ws + 38547968);             // [16384]
  unsigned short* g    = (unsigned short*)(ws + 38679040);   // [<=33152][1024] bf16 (compacted)
  unsigned short* xbf  = (unsigned short*)(ws + 38679040);   // alias: [16384][768]
  unsigned short* wt   = (unsigned short*)(ws + 63844864);   // alias: [768][768]
  unsigned short* y    = (unsigned short*)(ws + 106574336);  // [<=33152][768] bf16 (compacted)
  // end: 157,495,808 < ~198 MB proven available

  hipMemsetAsync(cnt, 0, NEXP * sizeof(int), stream);
  transpose_bf16_kernel<<<dim3(24, 24, 1), dim3(32, 8), 0, stream>>>(W, wt, 768, 768, 768, 589824);
  transpose_bf16_kernel<<<dim3(32, 24, 4), dim3(32, 8), 0, stream>>>(W1, w1t, 768, 1024, 768, 786432);
  transpose_bf16_kernel<<<dim3(24, 32, 4), dim3(32, 8), 0, stream>>>(W2, w2t, 1024, 768, 1024, 786432);
  wfg_kernel<<<13, 256, 0, stream>>>(W, Wg, b, bg, wfg, bgp);
  router_kernel<<<4096, 256, 0, stream>>>(x, wfg, bgp, rte, rtg, xbf);  // + fused x->bf16
  assign_kernel<<<64, 256, 0, stream>>>(rte, rtg, cnt, idx_tok, gate_sel, tok_slot);

  // GEMM1: t = bf16(x @ W + b)          [dense, 19.3 GF]  K=768 -> NT=24
  gemm_kernel<0, 8, 24><<<dim3(6, 128), 256, 0, stream>>>(
      xbf, 768, wt, 768, 768, b, nullptr, nullptr, nullptr, tbf, 768);
  // GEMM2: g[row] = bf16(gate * gelu(t[tok] @ W1_e + b1_e))   [gathered, 51.5 GF]  K=768
  gemm_kernel<1, 8, 24><<<dim3(8, 264), 256, 0, stream>>>(
      tbf, 768, w1t, 768, 1024, b1, idx_tok, gate_sel, cnt, g, 1024);
  // GEMM3: y[row] = bf16(g[row] @ W2_e)   [write-once, 51.5 GF]  K=1024 -> NT=32, N=768
  gemm_kernel<2, 8, 32><<<dim3(6, 264), 256, 0, stream>>>(
      g, 1024, w2t, 1024, 768, nullptr, nullptr, nullptr, cnt, y, 768);
  // combine: out[t] = y[slot1] + y[slot2] + c1*b2[e1] + c2*b2[e2]
  combine_kernel<<<4096, 256, 0, stream>>>(y, tok_slot, rtg, cnt, b2, out);
}

// Round 5
// 376.738 us; speedup vs baseline: 1.1973x; 1.0554x over previous
//
#include <hip/hip_runtime.h>

#define DIM 768
#define NEXP 4
#define DFF_ 1024
#define CAP 16384  // per-expert slot capacity (max possible = T)

typedef __attribute__((ext_vector_type(4))) float f32x4;
typedef __attribute__((ext_vector_type(8))) short s16x8;

__device__ __forceinline__ unsigned short f32_to_bf16(float f) {
  unsigned int u = __float_as_uint(f);
  unsigned int r = (u + 0x7FFFu + ((u >> 16) & 1u)) >> 16;  // RNE
  return (unsigned short)r;
}
__device__ __forceinline__ float bf16_to_f32(unsigned short u) {
  return __uint_as_float(((unsigned int)u) << 16);
}
// generic (__shared__) pointer -> 32-bit LDS byte offset, for asm ds_read vaddr
__device__ __forceinline__ unsigned lds_off(const void* p) {
  return (unsigned)(unsigned long long)(__attribute__((address_space(3))) const void*)p;
}

// ---------- pack fp32 [K][C] -> bf16 MFMA-frag-major blocks ----------
// Output block b = n16*(K/32) + kt is 1024 B: lane l (0..63) holds 8 bf16 =
// B[k = kt*32 + (l>>4)*8 + e][col = n16*16 + (l&15)], e=0..7 -- exactly the
// mfma_f32_16x16x32_bf16 B-operand fragment. One wave64 dwordx4 load of a
// block is 1024 contiguous bytes = perfectly coalesced.
__global__ void pack_bf16_kernel(const float* __restrict__ in,
                                 unsigned short* __restrict__ out,
                                 int K, int C) {
  const int t = threadIdx.x;
  const int lane = t & 63;
  const int pb = blockIdx.x * 4 + (t >> 6);
  const int KT = K >> 5;
  const int n16 = pb / KT, kt = pb - n16 * KT;
  const int z = blockIdx.z;
  in  += (size_t)z * K * C;
  out += (size_t)z * K * C;
  const int col = n16 * 16 + (lane & 15);
  const int k0 = kt * 32 + (lane >> 4) * 8;
  s16x8 vv;
#pragma unroll
  for (int e = 0; e < 8; e++) vv[e] = (short)f32_to_bf16(in[(size_t)(k0 + e) * C + col]);
  *(s16x8*)(out + (size_t)pb * 512 + lane * 8) = vv;
}

// ---------- Wfg = W @ Wg, bgp = b @ Wg + bg (fp32 router weights) ----------
__global__ void wfg_kernel(const float* __restrict__ W, const float* __restrict__ Wg,
                           const float* __restrict__ b, const float* __restrict__ bg,
                           float* __restrict__ wfg, float* __restrict__ bgp) {
  int gid = blockIdx.x * 256 + threadIdx.x;
  if (gid < DIM * NEXP) {
    int k = gid >> 2, e = gid & 3;
    const float* wr = W + (size_t)k * DIM;
    float acc = 0.f;
    for (int d = 0; d < DIM; d++) acc += wr[d] * Wg[d * NEXP + e];
    wfg[gid] = acc;
  } else if (gid < DIM * NEXP + NEXP) {
    int e = gid - DIM * NEXP;
    float acc = bg[e];
    for (int d = 0; d < DIM; d++) acc += b[d] * Wg[d * NEXP + e];
    bgp[e] = acc;
  }
}

// ---------- router (+ fused x->bf16 convert): fp32 logits, softmax, top2 ----------
__global__ void router_kernel(const float* __restrict__ x, const float* __restrict__ wfg,
                              const float* __restrict__ bgp,
                              int2* __restrict__ rte, float2* __restrict__ rtg,
                              unsigned short* __restrict__ xbf) {
  __shared__ float wfgS[DIM * NEXP];
  const int tid = threadIdx.x;
  for (int i = tid; i < DIM * NEXP; i += 256) wfgS[i] = wfg[i];
  __syncthreads();
  const int w = tid >> 6, lane = tid & 63;
  const size_t t = (size_t)blockIdx.x * 4 + w;
  const float* xr = x + t * DIM;
  unsigned short* xbr = xbf + t * DIM;
  float a0 = 0.f, a1 = 0.f, a2 = 0.f, a3 = 0.f;
#pragma unroll
  for (int i = 0; i < 6; i++) {
    int k = i * 128 + lane * 2;
    float2 xv = *(const float2*)(xr + k);
    ushort2 pk;
    pk.x = f32_to_bf16(xv.x);
    pk.y = f32_to_bf16(xv.y);
    *(ushort2*)(xbr + k) = pk;  // fused convert (saves a 50 MB re-read dispatch)
    a0 += xv.x * wfgS[k * 4 + 0] + xv.y * wfgS[k * 4 + 4];
    a1 += xv.x * wfgS[k * 4 + 1] + xv.y * wfgS[k * 4 + 5];
    a2 += xv.x * wfgS[k * 4 + 2] + xv.y * wfgS[k * 4 + 6];
    a3 += xv.x * wfgS[k * 4 + 3] + xv.y * wfgS[k * 4 + 7];
  }
#pragma unroll
  for (int off = 32; off > 0; off >>= 1) {
    a0 += __shfl_xor(a0, off);
    a1 += __shfl_xor(a1, off);
    a2 += __shfl_xor(a2, off);
    a3 += __shfl_xor(a3, off);
  }
  if (lane == 0) {
    float l[NEXP] = {a0 + bgp[0], a1 + bgp[1], a2 + bgp[2], a3 + bgp[3]};
    float m = fmaxf(fmaxf(l[0], l[1]), fmaxf(l[2], l[3]));
    float p[NEXP]; float s = 0.f;
#pragma unroll
    for (int e = 0; e < NEXP; e++) { p[e] = expf(l[e] - m); s += p[e]; }
#pragma unroll
    for (int e = 0; e < NEXP; e++) p[e] /= s;
    int i1 = 0;
#pragma unroll
    for (int e = 1; e < NEXP; e++) if (p[e] > p[i1]) i1 = e;  // ties -> lowest idx
    int i2 = -1;
#pragma unroll
    for (int e = 0; e < NEXP; e++) { if (e == i1) continue; if (i2 < 0 || p[e] > p[i2]) i2 = e; }
    float denom = p[i1] + p[i2];
    rte[t] = make_int2(i1, i2);
    rtg[t] = make_float2(p[i1] / denom, p[i2] / denom);
  }
}

// ---------- assign: per-expert slot lists + token->slot map ----------
__global__ void assign_kernel(const int2* __restrict__ rte, const float2* __restrict__ rtg,
                              int* __restrict__ cnt, int* __restrict__ idx_tok,
                              float* __restrict__ gate_sel, int2* __restrict__ tok_slot) {
  __shared__ int hist[NEXP];
  __shared__ int base[NEXP];
  const int tid = threadIdx.x;
  if (tid < NEXP) hist[tid] = 0;
  __syncthreads();
  const int t = blockIdx.x * 256 + tid;
  int2 e = rte[t];
  float2 g = rtg[t];
  int r1 = atomicAdd(&hist[e.x], 1);
  int r2 = atomicAdd(&hist[e.y], 1);
  __syncthreads();
  if (tid < NEXP) base[tid] = atomicAdd(&cnt[tid], hist[tid]);
  __syncthreads();
  int s1 = base[e.x] + r1, s2 = base[e.y] + r2;
  idx_tok[e.x * CAP + s1] = t;  gate_sel[e.x * CAP + s1] = g.x;
  idx_tok[e.y * CAP + s2] = t;  gate_sel[e.y * CAP + s2] = g.y;
  tok_slot[t] = make_int2((e.x << 14) | s1, (e.y << 14) | s2);  // packed e|slot
}

// ---------- combine: out[t] = y[row1] + y[row2] + c1*b2[e1] + c2*b2[e2] ----------
__global__ void combine_kernel(const unsigned short* __restrict__ y,
                               const int2* __restrict__ tok_slot,
                               const float2* __restrict__ rtg,
                               const int* __restrict__ cnts,
                               const float* __restrict__ b2,
                               float* __restrict__ out) {
  __shared__ float b2S[NEXP * DIM];
  const int tid = threadIdx.x;
  for (int i = tid; i < NEXP * DIM; i += 256) b2S[i] = b2[i];
  const int t0 = (cnts[0] + 127) >> 7, t1 = (cnts[1] + 127) >> 7, t2 = (cnts[2] + 127) >> 7;
  const int rb[NEXP] = {0, t0 * 128, (t0 + t1) * 128, (t0 + t1 + t2) * 128};
  __syncthreads();
  const int w = tid >> 6, lane = tid & 63;
  const size_t t = (size_t)blockIdx.x * 4 + w;
  int2 v = tok_slot[t];
  float2 cg = rtg[t];
  const int e1 = v.x >> 14, s1 = v.x & (CAP - 1);
  const int e2 = v.y >> 14, s2 = v.y & (CAP - 1);
  const unsigned short* y1 = y + (size_t)(rb[e1] + s1) * DIM;
  const unsigned short* y2 = y + (size_t)(rb[e2] + s2) * DIM;
  float* op = out + t * DIM;
  const float* bp1 = b2S + e1 * DIM;
  const float* bp2 = b2S + e2 * DIM;
#pragma unroll
  for (int k = 0; k < 12; k++) {
    int n = k * 64 + lane;
    op[n] = bf16_to_f32(y1[n]) + bf16_to_f32(y2[n]) + cg.x * bp1[n] + cg.y * bp2[n];
  }
}

// ---------- bf16 MFMA GEMM: 128x128 tile, A via LDS triple-buffer, B direct-to-reg ----------
// R5 theory: R4's counters (MfmaUtil 19%, ~50% idle on every pipe) showed the
// barrier-locked LDS path itself is the wall, not DMA latency. This round
// shrinks what flows through it: B (static weights, pre-PACKED into frag-major
// 1KB blocks) is loaded per-wave directly into registers with inline-asm
// global_load_dwordx4 (perfectly coalesced), double-buffered reg sets, no LDS,
// no barrier interaction. A keeps the R4 LDS pipeline (3 bufs, 2 DMA/wave/tile).
// vmcnt ledger (per-wave, issue order per iter = [B_{i+1}(4), A_{i+2}(2)]):
//   steady outstanding after gate = {A_{i+1}(2), B_{i+1}(4), A_{i+2}(2)} = 8
//   -> gate vmcnt(8) retires A_i,B_i. Tail: vmcnt(6) (leaves {A,B}_{NT-1}),
//   then vmcnt(0). Prologue [A0,B0,A1]=8 matches steady state at first gate.
// B reg sets ping-pong (static via x2-unrolled loop, rule 20). Barriers only
// protect A: BAR1 (all waves' A-DMA visible), BAR2 (A reads done before next
// ISSUE overwrites buf). Per-phase LDS reads halve (4 ds_read_b128).
// MODE 0: dense. MODE 1: row-gathered A + gelu*gate. MODE 2: contiguous A.
template <int MODE, int CH, int NT>
__launch_bounds__(256, 3)
__global__ void gemm_kernel(const unsigned short* __restrict__ A, const int lda,
                            const unsigned short* __restrict__ Bp, const int ldb,
                            const int N,
                            const float* __restrict__ bias,
                            const int* __restrict__ idx_tok,
                            const float* __restrict__ gate_sel,
                            const int* __restrict__ cnts,
                            unsigned short* __restrict__ outB, const int ldo) {
  const int lin = blockIdx.y * gridDim.x + blockIdx.x;
  const int nT = gridDim.x;
  const int xcd = lin & 7, t8 = lin >> 3;
  int bn = 0, bm0 = 0;
  int bmLoc = 0, cnt = 1 << 30, segBase = 0, gRow0 = 0;
  const unsigned short* Bt = Bp;

  if constexpr (MODE == 0) {
    const int perXcd = gridDim.y >> 3;
    const int mi = t8 % CH;
    const int rest = t8 / CH;
    bn = rest % nT;
    const int mc = rest / nT;
    bm0 = (xcd * perXcd + mc * CH + mi) * 128;
  } else {
    const int c0 = cnts[0], c1 = cnts[1], c2 = cnts[2], c3 = cnts[3];
    const int t0 = (c0 + 127) >> 7, t1 = (c1 + 127) >> 7,
              t2 = (c2 + 127) >> 7, t3 = (c3 + 127) >> 7;
    const int p1 = t0, p2 = p1 + t1, p3 = p2 + t2, tot = p3 + t3;
    const int perXcd = (tot + 7) >> 3;  // equal share of ACTIVE tiles per XCD
    bn = t8 % nT;
    const int mloc = t8 / nT;           // n fastest within XCD -> A-tile L2 reuse
    if (mloc >= perXcd) return;
    const int mIdx = xcd * perXcd + mloc;
    if (mIdx >= tot) return;
    const int seg = (mIdx >= p2) ? ((mIdx >= p3) ? 3 : 2) : ((mIdx >= p1) ? 1 : 0);
    const int pre = (seg == 3) ? p3 : (seg == 2) ? p2 : (seg == 1) ? p1 : 0;
    bmLoc = (mIdx - pre) * 128;
    segBase = seg * CAP;
    gRow0 = mIdx * 128;                 // compacted-padded row base = tileIdx*128
    cnt = (seg == 3) ? c3 : (seg == 2) ? c2 : (seg == 1) ? c1 : c0;
    Bt += (size_t)seg * N * ldb;        // per-seg packed panel = N*K elems
    if constexpr (MODE == 1) bias += (size_t)seg * N;
  }

  __shared__ unsigned short As[3][128 * 32];  // 24 KiB (3 bufs)
  __shared__ int idxS[128];
  __shared__ float gateS[128];

  const int tid = threadIdx.x;
  const int w = tid >> 6;
  const int lane = tid & 63;

  if constexpr (MODE == 1) {
    if (tid < 128) {
      int r = bmLoc + tid;
      int cl = (r < cnt) ? r : bmLoc;  // clamp to block's first (valid) row
      idxS[tid] = idx_tok[segBase + cl];
      gateS[tid] = gate_sel[segBase + cl];
    }
    __syncthreads();
  }

  // per-thread A staging rows are constant across K
  const int r0 = tid >> 2, r1 = 64 + r0;
  const int gq = (tid & 3) ^ (r0 & 3);  // quad XOR swizzle (r1&3 == r0&3)
  const unsigned short *aP0, *aP1;
  if constexpr (MODE == 0) {
    aP0 = A + (size_t)(bm0 + r0) * lda + gq * 8;
    aP1 = A + (size_t)(bm0 + r1) * lda + gq * 8;
  } else if constexpr (MODE == 1) {
    aP0 = A + (size_t)idxS[r0] * lda + gq * 8;
    aP1 = A + (size_t)idxS[r1] * lda + gq * 8;
  } else {
    aP0 = A + (size_t)(gRow0 + r0) * lda + gq * 8;  // contiguous compacted rows
    aP1 = A + (size_t)(gRow0 + r1) * lda + gq * 8;
  }

  const int quad = lane >> 4;
  const int m16 = lane & 15;
  const int wm = (w & 1) * 64;
  const int wn = (w >> 1) * 64;
  const int sw = (quad ^ (m16 & 3)) * 16;  // de-swizzle

  const unsigned aBase0 = lds_off(&As[0][0]);
  const unsigned aRd = (unsigned)((wm + m16) * 64 + sw);

  // B packed frag pointers: block (n16, kt) at (n16*NT + kt)*512 elems; this
  // wave's 4 col-blocks n16 = bn*8 + (w>>1)*4 + j; advance 512 elems per tile.
  const unsigned short* bp0 = Bt + (size_t)(bn * 8 + (w >> 1) * 4 + 0) * NT * 512 + lane * 8;
  const unsigned short* bp1 = Bt + (size_t)(bn * 8 + (w >> 1) * 4 + 1) * NT * 512 + lane * 8;
  const unsigned short* bp2 = Bt + (size_t)(bn * 8 + (w >> 1) * 4 + 2) * NT * 512 + lane * 8;
  const unsigned short* bp3 = Bt + (size_t)(bn * 8 + (w >> 1) * 4 + 3) * NT * 512 + lane * 8;

  f32x4 acc[4][4];
#pragma unroll
  for (int i = 0; i < 4; i++)
#pragma unroll
    for (int j = 0; j < 4; j++) acc[i][j] = (f32x4){0.f, 0.f, 0.f, 0.f};

  s16x8 br0[4], br1[4];  // B frag double-buffer (register sets, static-indexed)

#define GLL(src, dst)                                                              \
  __builtin_amdgcn_global_load_lds((const __attribute__((address_space(1))) void*)(src), \
                                   (__attribute__((address_space(3))) void*)(dst), 16, 0, 0)
#define ISSUE_A(off, kk)                                                 \
  {                                                                      \
    char* la0 = (char*)&As[0][0] + (off) + w * 1024;                     \
    GLL(aP0 + (kk), la0);                                                \
    GLL(aP1 + (kk), la0 + 4096);                                         \
  }
#define LOADB(SET)                                                                   \
  {                                                                                  \
    asm volatile("global_load_dwordx4 %0, %1, off" : "=v"(br##SET[0]) : "v"(bp0));   \
    asm volatile("global_load_dwordx4 %0, %1, off" : "=v"(br##SET[1]) : "v"(bp1));   \
    asm volatile("global_load_dwordx4 %0, %1, off" : "=v"(br##SET[2]) : "v"(bp2));   \
    asm volatile("global_load_dwordx4 %0, %1, off" : "=v"(br##SET[3]) : "v"(bp3));   \
    bp0 += 512; bp1 += 512; bp2 += 512; bp3 += 512;                                  \
  }
#define DSR(dst, addr, imm) \
  asm volatile("ds_read_b128 %0, %1 offset:" #imm : "=v"(dst) : "v"(addr))
// One K-step: counted gate (A_i DMA + B_i regs retired; newer stay in flight),
// BAR, 4 asm A-frag reads, lgkm+fence, BAR (frees cur A-buf), MFMA on br<SET>.
#define KSTEP(GATE, SET)                                                     \
  {                                                                          \
    asm volatile("s_waitcnt vmcnt(" #GATE ")" ::: "memory");                 \
    __builtin_amdgcn_sched_barrier(0);                                       \
    __builtin_amdgcn_s_barrier();                                            \
    asm volatile("" ::: "memory");                                           \
    s16x8 af[4];                                                             \
    const unsigned aAd = aBase0 + curOff + aRd;                              \
    DSR(af[0], aAd, 0);                                                      \
    DSR(af[1], aAd, 1024);                                                   \
    DSR(af[2], aAd, 2048);                                                   \
    DSR(af[3], aAd, 3072);                                                   \
    asm volatile("s_waitcnt lgkmcnt(0)" ::: "memory");                       \
    __builtin_amdgcn_sched_barrier(0);                                       \
    __builtin_amdgcn_s_barrier();                                            \
    asm volatile("" ::: "memory");                                           \
    __builtin_amdgcn_s_setprio(1);                                           \
    _Pragma("unroll") for (int i_ = 0; i_ < 4; i_++)                         \
    _Pragma("unroll") for (int j_ = 0; j_ < 4; j_++)                         \
      acc[i_][j_] = __builtin_amdgcn_mfma_f32_16x16x32_bf16(af[i_], br##SET[j_], \
                                                            acc[i_][j_], 0, 0, 0); \
    __builtin_amdgcn_s_setprio(0);                                           \
    curOff = (curOff == 16384u) ? 0u : curOff + 8192u;                       \
  }

  // prologue: A tiles 0,1 DMA + B tile 0 regs in flight (queue: A0,B0,A1 = 8)
  ISSUE_A(0, 0);
  LOADB(0);
  ISSUE_A(8192, 32);
  unsigned curOff = 0;       // LDS byte offset of A buffer being computed
  unsigned stOff = 16384;    // LDS byte offset of A stage target (tile i+2)
  int kk = 64;               // element-k of A stage target

  static_assert(NT >= 4 && (NT & 1) == 0, "NT must be even, >= 4");
#pragma unroll 1
  for (int ii = 0; ii < (NT - 2) / 2; ii++) {
    LOADB(1);                                   // B_{i+1}
    ISSUE_A(stOff, kk);                         // A_{i+2}
    kk += 32;
    stOff = (stOff == 16384u) ? 0u : stOff + 8192u;
    KSTEP(8, 0);                                // tile i (even)
    LOADB(0);
    ISSUE_A(stOff, kk);
    kk += 32;
    stOff = (stOff == 16384u) ? 0u : stOff + 8192u;
    KSTEP(8, 1);                                // tile i+1 (odd)
  }
  LOADB(1);                                     // B_{NT-1}
  KSTEP(6, 0);                                  // tile NT-2 (leaves {A,B}_{NT-1})
  KSTEP(0, 1);                                  // tile NT-1: drain

#undef KSTEP
#undef DSR
#undef LOADB
#undef ISSUE_A
#undef GLL

#pragma unroll
  for (int i = 0; i < 4; i++) {
    const int rloc = wm + i * 16 + quad * 4;
#pragma unroll
    for (int j = 0; j < 4; j++) {
      const int col = bn * 128 + wn + j * 16 + m16;
      if constexpr (MODE == 0) {
        float bv = bias[col];
#pragma unroll
        for (int r = 0; r < 4; r++)
          outB[(size_t)(bm0 + rloc + r) * ldo + col] = f32_to_bf16(acc[i][j][r] + bv);
      } else if constexpr (MODE == 1) {
        float bv = bias[col];
#pragma unroll
        for (int r = 0; r < 4; r++) {
          if (bmLoc + rloc + r < cnt) {
            float v = acc[i][j][r] + bv;
            float t3 = v + 0.044715f * v * v * v;
            float e2 = exp2f(t3 * 2.302208206984525f);  // e^{2u}, u=sqrt(2/pi)(v+0.044715v^3)
            float rc = __builtin_amdgcn_rcpf(1.0f + e2);
            float g = v - v * rc;
            outB[(size_t)(gRow0 + rloc + r) * ldo + col] = f32_to_bf16(g * gateS[rloc + r]);
          }
        }
      } else {
#pragma unroll
        for (int r = 0; r < 4; r++) {
          if (bmLoc + rloc + r < cnt)
            outB[(size_t)(gRow0 + rloc + r) * ldo + col] = f32_to_bf16(acc[i][j][r]);
        }
      }
    }
  }
}

extern "C" void kernel_launch(void* const* d_in, const int* in_sizes, int n_in,
                              void* d_out, int out_size, void* d_ws, size_t ws_size,
                              hipStream_t stream) {
  (void)in_sizes; (void)n_in; (void)out_size; (void)ws_size;
  const float* x  = (const float*)d_in[0];
  const float* W  = (const float*)d_in[1];
  const float* b  = (const float*)d_in[2];
  const float* Wg = (const float*)d_in[3];
  const float* bg = (const float*)d_in[4];
  const float* W1 = (const float*)d_in[5];
  const float* b1 = (const float*)d_in[6];
  const float* W2 = (const float*)d_in[7];
  const float* b2 = (const float*)d_in[8];
  float* out = (float*)d_out;
  char* ws = (char*)d_ws;

  // workspace layout (bytes); xbf/wp alias the g region (dead before g is written)
  unsigned short* tbf  = (unsigned short*)(ws + 0);          // [16384][768] bf16
  unsigned short* w1p  = (unsigned short*)(ws + 25165824);   // [4] packed 768x1024 bf16
  unsigned short* w2p  = (unsigned short*)(ws + 31457280);   // [4] packed 1024x768 bf16
  float* wfg           = (float*)(ws + 37748736);            // [768][4]
  float* bgp           = (float*)(ws + 37761024);            // [4]
  int2*  rte           = (int2*)(ws + 37761280);             // [16384]
  float2* rtg          = (float2*)(ws + 37892352);           // [16384]
  int*   cnt           = (int*)(ws + 38023424);              // [4]
  int*   idx_tok       = (int*)(ws + 38023680);              // [4][CAP]
  float* gate_sel      = (float*)(ws + 38285824);            // [4][CAP]
  int2*  tok_slot      = (int2*)(ws + 38547968);             // [16384]
  unsigned short* g    = (unsigned short*)(ws + 38679040);   // [<=33152][1024] bf16 (compacted)
  unsigned short* xbf  = (unsigned short*)(ws + 38679040);   // alias: [16384][768]
  unsigned short* wp   = (unsigned short*)(ws + 63844864);   // alias: packed 768x768
  unsigned short* y    = (unsigned short*)(ws + 106574336);  // [<=33152][768] bf16 (compacted)
  // end: 157,495,808 < ~198 MB proven available

  hipMemsetAsync(cnt, 0, NEXP * sizeof(int), stream);
  // pack B matrices into MFMA-frag-major order (replaces the old transposes)
  pack_bf16_kernel<<<dim3(288, 1, 1), 256, 0, stream>>>(W, wp, 768, 768);
  pack_bf16_kernel<<<dim3(384, 1, 4), 256, 0, stream>>>(W1, w1p, 768, 1024);
  pack_bf16_kernel<<<dim3(384, 1, 4), 256, 0, stream>>>(W2, w2p, 1024, 768);
  wfg_kernel<<<13, 256, 0, stream>>>(W, Wg, b, bg, wfg, bgp);
  router_kernel<<<4096, 256, 0, stream>>>(x, wfg, bgp, rte, rtg, xbf);  // + fused x->bf16
  assign_kernel<<<64, 256, 0, stream>>>(rte, rtg, cnt, idx_tok, gate_sel, tok_slot);

  // GEMM1: t = bf16(x @ W + b)          [dense, 19.3 GF]  K=768 -> NT=24
  gemm_kernel<0, 8, 24><<<dim3(6, 128), 256, 0, stream>>>(
      xbf, 768, wp, 768, 768, b, nullptr, nullptr, nullptr, tbf, 768);
  // GEMM2: g[row] = bf16(gate * gelu(t[tok] @ W1_e + b1_e))   [gathered, 51.5 GF]  K=768
  gemm_kernel<1, 8, 24><<<dim3(8, 264), 256, 0, stream>>>(
      tbf, 768, w1p, 768, 1024, b1, idx_tok, gate_sel, cnt, g, 1024);
  // GEMM3: y[row] = bf16(g[row] @ W2_e)   [write-once, 51.5 GF]  K=1024 -> NT=32, N=768
  gemm_kernel<2, 8, 32><<<dim3(6, 264), 256, 0, stream>>>(
      g, 1024, w2p, 1024, 768, nullptr, nullptr, nullptr, cnt, y, 768);
  // combine: out[t] = y[slot1] + y[slot2] + c1*b2[e1] + c2*b2[e2]
  combine_kernel<<<4096, 256, 0, stream>>>(y, tok_slot, rtg, cnt, b2, out);
}